// Round 16
// baseline (1584.127 us; speedup 1.0000x reference)
//
#include <hip/hip_runtime.h>
#include <math.h>

#define BB 256
#define AA 3
#define NN 1000
#define DD 128
#define HH 8
#define FFD 512
#define CLIPV 10.0f

typedef unsigned short u16;
typedef __attribute__((ext_vector_type(8))) short bf16x8;
typedef __attribute__((ext_vector_type(4))) float f32x4;

#define MFMA16(a, b, c) __builtin_amdgcn_mfma_f32_16x16x32_bf16(a, b, c, 0, 0, 0)

// fast exp2: bare v_exp_f32 (compiler handles transcendental hazards).
#if defined(__has_builtin)
#if __has_builtin(__builtin_amdgcn_exp2f)
#define EXP2(x) __builtin_amdgcn_exp2f(x)
#endif
#endif
#ifndef EXP2
#define EXP2(x) __expf((x) * 0.69314718055994531f)
#endif

__device__ __forceinline__ u16 f2b(float f) {
  union { float f; unsigned u; } v; v.f = f;
  unsigned r = (v.u + 0x7fffu + ((v.u >> 16) & 1u)) >> 16;
  return (u16)r;
}
__device__ __forceinline__ float b2f(u16 h) {
  union { float f; unsigned u; } v; v.u = ((unsigned)h) << 16;
  return v.f;
}
__device__ __forceinline__ unsigned cvtpk(float lo, float hi) {
  unsigned r;
  asm("v_cvt_pk_bf16_f32 %0, %1, %2" : "=v"(r) : "v"(lo), "v"(hi));
  return r;
}

// ---------------------------------------------------------------- K0: weight prep
__global__ __launch_bounds__(256) void k_transpose(
    const float* __restrict__ Wo, const float* __restrict__ W1,
    const float* __restrict__ W2, const float* __restrict__ Wm,
    const float* __restrict__ Wq, const float* __restrict__ Wk,
    const float* __restrict__ Wv,
    float* __restrict__ WmT, u16* __restrict__ Wqkvb,
    u16* __restrict__ Wob, u16* __restrict__ W1b, u16* __restrict__ W2b) {
  int idx = blockIdx.x * 256 + threadIdx.x;
  if (idx < 49152) { int e = idx / 384, r = idx % 384; WmT[idx] = Wm[r * 128 + e]; }
  if (idx < 49152) {
    int m = idx >> 14, rem = idx & 16383;
    const float* src = (m == 0) ? Wq : (m == 1) ? Wk : Wv;
    Wqkvb[idx] = f2b(src[rem]);
  }
  if (idx < 16384) Wob[idx] = f2b(Wo[idx]);
  if (idx < 65536) { W1b[idx] = f2b(W1[idx]); W2b[idx] = f2b(W2[idx]); }
}

// ---------------------------------------------------------------- K1: setup (context only)
__global__ __launch_bounds__(256) void k_setup(
    const float* __restrict__ location, const float* __restrict__ max_load,
    const float* __restrict__ speed, const int* __restrict__ next_agent,
    const int* __restrict__ position, const float* __restrict__ load,
    const float* __restrict__ nef, const float* __restrict__ depot,
    const float* __restrict__ graph, const float* __restrict__ W_ctx,
    const float* __restrict__ b_ctx, float* __restrict__ ctx_out) {
  int b = blockIdx.x;
  int tid = threadIdx.x;
  __shared__ float ai[131];
  int na = next_agent[b];
  if (tid < 128) {
    int ap = position[b * AA + na];
    ai[tid] = nef[((size_t)b * 128 + tid) * NN + ap];
  } else if (tid == 128) ai[128] = load[b * AA + na];
  else if (tid == 129) ai[129] = max_load[b * AA + na];
  else if (tid == 130) ai[130] = speed[b * AA + na];
  __syncthreads();
  if (tid < 128) {
    float acc = b_ctx[tid] + depot[b * 128 + tid] + graph[b * 128 + tid];
    for (int i = 0; i < 131; ++i) acc += W_ctx[tid * 131 + i] * ai[i];
    ctx_out[b * 128 + tid] = acc;
  }
}

// ---------------------------------------------------------------- K2: node features + embed -> h0b bf16 [B,N,128]
__global__ __launch_bounds__(128) void k_ne(
    const float* __restrict__ location, const int* __restrict__ next_agent,
    const int* __restrict__ position, const float* __restrict__ tta,
    const float* __restrict__ load, const float* __restrict__ demand,
    const float* __restrict__ speed, const float* __restrict__ W_na,
    const float* __restrict__ b_na, u16* __restrict__ h0b) {
  int tile = blockIdx.x, b = blockIdx.y, tid = threadIdx.x;
  __shared__ float nif[6][16];
  __shared__ int ordS[AA];
  __shared__ float alxS[AA], alyS[AA], spdS[AA], ttsS[AA], ldS[AA];
  if (tid == 0) {
    int na = next_agent[b];
    int c = 1; ordS[0] = na;
    for (int a = 0; a < AA; ++a) if (a != na) ordS[c++] = a;
    for (int s = 0; s < AA; ++s) {
      int g = ordS[s];
      int p = position[b * AA + g];
      alxS[s] = location[((size_t)b * NN + p) * 2];
      alyS[s] = location[((size_t)b * NN + p) * 2 + 1];
      spdS[s] = speed[b * AA + g];
      ttsS[s] = tta[b * AA + g];
      ldS[s]  = load[b * AA + g];
    }
  }
  __syncthreads();
  if (tid < 16) {
    int n = tile * 16 + tid;
    if (n < NN) {
      float lx = location[((size_t)b * NN + n) * 2];
      float ly = location[((size_t)b * NN + n) * 2 + 1];
      float dm = demand[(size_t)b * NN + n];
      #pragma unroll
      for (int s = 0; s < AA; ++s) {
        float dr = dm / ldS[s];
        if (dr > 1.0f) dr = -1.0f;
        if (dr != dr) dr = 0.0f;
        float dx = alxS[s] - lx, dy = alyS[s] - ly;
        float dist = sqrtf(dx * dx + dy * dy);
        float tt = (ttsS[s] == -1.0f) ? -1.0f : dist / spdS[s] + ttsS[s];
        nif[s][tid] = dr;
        nif[3 + s][tid] = tt;
      }
    } else {
      #pragma unroll
      for (int f = 0; f < 6; ++f) nif[f][tid] = 0.0f;
    }
  }
  __syncthreads();
  int d = tid;
  float w[6];
  #pragma unroll
  for (int i = 0; i < 6; ++i) w[i] = W_na[d * 6 + i];
  float bias = b_na[d];
  for (int i = 0; i < 16; ++i) {
    int n = tile * 16 + i;
    if (n >= NN) break;
    float acc = bias;
    #pragma unroll
    for (int f = 0; f < 6; ++f) acc += w[f] * nif[f][i];
    h0b[((size_t)b * NN + n) * 128 + d] = f2b(acc);
  }
}

// ---------------------------------------------------------------- K3: QKV projection (MFMA bf16) -> head-blocked Qh,Kh,Vh
__global__ __launch_bounds__(256, 2) void k_qkv(
    const u16* __restrict__ h0b, const u16* __restrict__ Wqkvb,
    const float* __restrict__ bq, const float* __restrict__ bk,
    const float* __restrict__ bv,
    u16* __restrict__ Qh, u16* __restrict__ Kh, u16* __restrict__ Vh) {
  int tile = blockIdx.x, b = blockIdx.y;
  int tid = threadIdx.x;
  int w = tid >> 6, l = tid & 63, lo = l & 15, g = l >> 4;
  int n0 = tile * 64 + w * 16;
  f32x4 acc[3][8];
  #pragma unroll
  for (int m = 0; m < 3; ++m)
    #pragma unroll
    for (int ct = 0; ct < 8; ++ct) acc[m][ct] = (f32x4){0.f, 0.f, 0.f, 0.f};

  for (int ks = 0; ks < 4; ++ks) {
    int n = n0 + lo; if (n > NN - 1) n = NN - 1;
    bf16x8 af = *(const bf16x8*)&h0b[((size_t)(b * NN + n)) * 128 + ks * 32 + g * 8];
    #pragma unroll
    for (int m = 0; m < 3; ++m) {
      #pragma unroll
      for (int ct = 0; ct < 8; ++ct) {
        bf16x8 bf_ = *(const bf16x8*)&Wqkvb[(size_t)m * 16384 + (ct * 16 + lo) * 128 + ks * 32 + g * 8];
        acc[m][ct] = MFMA16(af, bf_, acc[m][ct]);
      }
    }
  }
  const float* biases[3] = {bq, bk, bv};
  u16* outs[3] = {Qh, Kh, Vh};
  #pragma unroll
  for (int m = 0; m < 3; ++m) {
    float scale = (m == 0) ? 0.25f * 1.44269504088896f : 1.0f;
    #pragma unroll
    for (int ct = 0; ct < 8; ++ct) {      // ct == head index, lo == j within head
      int o = ct * 16 + lo;
      float bias = biases[m][o];
      float vals[4] = {acc[m][ct].x, acc[m][ct].y, acc[m][ct].z, acc[m][ct].w};
      #pragma unroll
      for (int r = 0; r < 4; ++r) {
        int n = n0 + g * 4 + r;
        if (n < NN)
          outs[m][((size_t)(b * HH + ct) * NN + n) * 16 + lo] = f2b((vals[r] + bias) * scale);
      }
    }
  }
}

// ---------------------------------------------------------------- K4: flash attention, max-free softmax + MFMA ones-denominator
__global__ __launch_bounds__(256, 4) void k_attn9(
    const u16* __restrict__ Qh, const u16* __restrict__ Kh,
    const u16* __restrict__ Vh, u16* __restrict__ attnbH) {
  __shared__ u16 Vt[16 * 1036];  // Vt[d][key], stride 1036 (518 words ≡ 6 mod 32): 0 conflicts
  int h = blockIdx.x, b = blockIdx.y;
  int bh = b * HH + h;
  const u16* Qp = Qh + (size_t)bh * NN * 16;
  const u16* Kp = Kh + (size_t)bh * NN * 16;
  const u16* Vp = Vh + (size_t)bh * NN * 16;
  int tid = threadIdx.x;
  {
    int half = tid & 1, kr = tid >> 1;
    for (int it = 0; it < 8; ++it) {
      int key = it * 128 + kr;
      int ksrc = key < NN ? key : NN - 1;
      union { uint4 q; u16 s[8]; } u;
      u.q = *(const uint4*)&Vp[(size_t)ksrc * 16 + half * 8];
      #pragma unroll
      for (int j = 0; j < 8; ++j) {
        u16 val = (key < NN) ? u.s[j] : (u16)0;
        Vt[(half * 8 + j) * 1036 + key] = val;
      }
    }
  }
  __syncthreads();

  int w = tid >> 6, l = tid & 63, lo = l & 15, g = l >> 4;
  const bf16x8 zfrag = {0, 0, 0, 0, 0, 0, 0, 0};
  const short one_b = (short)0x3F80;  // bf16 1.0
  const bf16x8 ones = {one_b, one_b, one_b, one_b, one_b, one_b, one_b, one_b};

  for (int tg = 0; tg < 4; ++tg) {
    int qbase = w * 256 + tg * 64;

    bf16x8 qf[4];
    #pragma unroll
    for (int t = 0; t < 4; ++t) {
      if (g < 2) {
        int q = qbase + t * 16 + lo; if (q > NN - 1) q = NN - 1;
        qf[t] = *(const bf16x8*)&Qp[(size_t)q * 16 + g * 8];
      } else qf[t] = zfrag;
    }

    f32x4 of[4], lacc[4];
    #pragma unroll
    for (int t = 0; t < 4; ++t) {
      of[t] = (f32x4){0.f, 0.f, 0.f, 0.f};
      lacc[t] = (f32x4){0.f, 0.f, 0.f, 0.f};
    }

    for (int c = 0; c < 16; ++c) {
      bf16x8 kf[4];
      #pragma unroll
      for (int kt = 0; kt < 4; ++kt) {
        if (g < 2) {
          int krow = c * 64 + kt * 16 + lo; if (krow > NN - 1) krow = NN - 1;
          kf[kt] = *(const bf16x8*)&Kp[(size_t)krow * 16 + g * 8];
        } else kf[kt] = zfrag;
      }
      bf16x8 vf[2];
      #pragma unroll
      for (int vt = 0; vt < 2; ++vt) {
        union { bf16x8 v; ushort4 h4[2]; } uu;
        int key0 = c * 64 + vt * 32 + g * 4;
        uu.h4[0] = *(const ushort4*)&Vt[lo * 1036 + key0];
        uu.h4[1] = *(const ushort4*)&Vt[lo * 1036 + key0 + 16];
        vf[vt] = uu.v;
      }
      #pragma unroll
      for (int t = 0; t < 4; ++t) {
        f32x4 sf[4];
        #pragma unroll
        for (int kt = 0; kt < 4; ++kt) {
          f32x4 zz = (f32x4){0.f, 0.f, 0.f, 0.f};
          sf[kt] = MFMA16(kf[kt], qf[t], zz);
        }
        float sc[16];
        #pragma unroll
        for (int kt = 0; kt < 4; ++kt) {
          sc[kt * 4 + 0] = sf[kt].x; sc[kt * 4 + 1] = sf[kt].y;
          sc[kt * 4 + 2] = sf[kt].z; sc[kt * 4 + 3] = sf[kt].w;
        }
        if (c == 15) {
          #pragma unroll
          for (int kt = 0; kt < 4; ++kt)
            #pragma unroll
            for (int r = 0; r < 4; ++r)
              if (960 + kt * 16 + g * 4 + r >= NN) sc[kt * 4 + r] = -1e30f;
        }
        float e[16];
        #pragma unroll
        for (int i = 0; i < 16; ++i) e[i] = EXP2(sc[i]);
        union { bf16x8 v; unsigned u[4]; } p0, p1;
        #pragma unroll
        for (int j = 0; j < 4; ++j) {
          p0.u[j] = cvtpk(e[2 * j], e[2 * j + 1]);
          p1.u[j] = cvtpk(e[8 + 2 * j], e[8 + 2 * j + 1]);
        }
        of[t] = MFMA16(vf[0], p0.v, of[t]);
        of[t] = MFMA16(vf[1], p1.v, of[t]);
        lacc[t] = MFMA16(ones, p0.v, lacc[t]);
        lacc[t] = MFMA16(ones, p1.v, lacc[t]);
      }
    }
    #pragma unroll
    for (int t = 0; t < 4; ++t) {
      float inv = 1.0f / lacc[t].x;
      int q = qbase + t * 16 + lo;
      if (q < NN) {
        union { ushort4 s; unsigned u[2]; } o4;
        o4.u[0] = cvtpk(of[t].x * inv, of[t].y * inv);
        o4.u[1] = cvtpk(of[t].z * inv, of[t].w * inv);
        *(ushort4*)&attnbH[((size_t)bh * NN + q) * 16 + g * 4] = o4.s;
      }
    }
  }
}

// ---------------------------------------------------------------- K_FF2: MFMA O-proj + residual + FF -> h2T [B,128,N]
// No min-waves bound: LDS already caps at 2 blocks/CU (2 waves/SIMD -> 256 VGPR budget); let the
// allocator use ~170 VGPRs and eliminate the accumulator spills seen at the forced 128 cap.
__global__ __launch_bounds__(256) void k_ff2(
    const u16* __restrict__ h0b, const u16* __restrict__ attnbH,
    const u16* __restrict__ Wob, const float* __restrict__ bo,
    const u16* __restrict__ W1b, const float* __restrict__ b1,
    const u16* __restrict__ W2b, const float* __restrict__ b2,
    float* __restrict__ h2T) {
  __shared__ __align__(16) unsigned char smemraw[69632];
  u16* h1s = (u16*)smemraw;               // [4 waves][32 rows][136]
  u16* fs  = ((u16*)smemraw) + 4 * 32 * 136;
  float* h2s = (float*)smemraw;            // [128][132] (reused after sync)

  int b = blockIdx.y;
  int tid = threadIdx.x;
  int w = tid >> 6, l = tid & 63, lo = l & 15, g = l >> 4;
  int nb = blockIdx.x * 128 + w * 32;

  f32x4 acc3[2][8];

  float bo8[8], b28[8];
  #pragma unroll
  for (int ct = 0; ct < 8; ++ct) { bo8[ct] = bo[ct * 16 + lo]; b28[ct] = b2[ct * 16 + lo]; }

  // stage this wave's h0 tile (32 rows x 128) into fs via vector loads (wave-private)
  #pragma unroll
  for (int j = 0; j < 8; ++j) {
    int row = j * 4 + g;
    int n = nb + row; if (n > NN - 1) n = NN - 1;
    uint4 v = *(const uint4*)&h0b[((size_t)(b * NN + n)) * 128 + lo * 8];
    *(uint4*)&fs[(size_t)(w * 32 + row) * 136 + lo * 8] = v;
  }

  // ---------------- GEMM1: h1 = attn @ Wo^T + bo + h0 ; acc3 = h1 + b2
  #pragma unroll
  for (int s = 0; s < 2; ++s) {
    bf16x8 af[4];
    {
      int n = nb + s * 16 + lo; if (n > NN - 1) n = NN - 1;
      #pragma unroll
      for (int ks = 0; ks < 4; ++ks) {
        int hidx = ks * 2 + (g >> 1), j0 = (g & 1) * 8;
        af[ks] = *(const bf16x8*)&attnbH[((size_t)(b * HH + hidx) * NN + n) * 16 + j0];
      }
    }
    f32x4 a1[8];
    #pragma unroll
    for (int ct = 0; ct < 8; ++ct) a1[ct] = (f32x4){0.f, 0.f, 0.f, 0.f};
    #pragma unroll
    for (int ks = 0; ks < 4; ++ks) {
      #pragma unroll
      for (int ct = 0; ct < 8; ++ct) {
        bf16x8 bw = *(const bf16x8*)&Wob[(size_t)(ct * 16 + lo) * 128 + ks * 32 + g * 8];
        a1[ct] = MFMA16(af[ks], bw, a1[ct]);
      }
    }
    #pragma unroll
    for (int ct = 0; ct < 8; ++ct) {
      int d = ct * 16 + lo;
      float vals[4] = {a1[ct].x, a1[ct].y, a1[ct].z, a1[ct].w};
      #pragma unroll
      for (int r = 0; r < 4; ++r) {
        int lrow = s * 16 + g * 4 + r;
        float h0v = b2f(fs[(size_t)(w * 32 + lrow) * 136 + d]);
        float h1v = vals[r] + bo8[ct] + h0v;
        h1s[(size_t)(w * 32 + lrow) * 136 + d] = f2b(h1v);
        vals[r] = h1v + b28[ct];
      }
      acc3[s][ct] = (f32x4){vals[0], vals[1], vals[2], vals[3]};
    }
  }

  // ---------------- 4 chunks of 128 FF cols: GEMM2 (relu) + GEMM3 (accumulate)
  for (int fc = 0; fc < 4; ++fc) {
    bf16x8 a2[2][4];
    #pragma unroll
    for (int s = 0; s < 2; ++s)
      #pragma unroll
      for (int ks = 0; ks < 4; ++ks)
        a2[s][ks] = *(const bf16x8*)&h1s[(size_t)(w * 32 + s * 16 + lo) * 136 + ks * 32 + g * 8];
    f32x4 acc2[2][8];
    #pragma unroll
    for (int s = 0; s < 2; ++s)
      #pragma unroll
      for (int ct = 0; ct < 8; ++ct) acc2[s][ct] = (f32x4){0.f, 0.f, 0.f, 0.f};
    #pragma unroll
    for (int ks = 0; ks < 4; ++ks) {
      #pragma unroll
      for (int ct = 0; ct < 8; ++ct) {
        bf16x8 bw = *(const bf16x8*)&W1b[(size_t)(fc * 128 + ct * 16 + lo) * 128 + ks * 32 + g * 8];
        acc2[0][ct] = MFMA16(a2[0][ks], bw, acc2[0][ct]);
        acc2[1][ct] = MFMA16(a2[1][ks], bw, acc2[1][ct]);
      }
    }
    #pragma unroll
    for (int ct = 0; ct < 8; ++ct) {
      float b1f = b1[fc * 128 + ct * 16 + lo];
      #pragma unroll
      for (int s = 0; s < 2; ++s) {
        float vals[4] = {acc2[s][ct].x, acc2[s][ct].y, acc2[s][ct].z, acc2[s][ct].w};
        #pragma unroll
        for (int r = 0; r < 4; ++r) {
          float v = fmaxf(vals[r] + b1f, 0.0f);
          fs[(size_t)(w * 32 + s * 16 + g * 4 + r) * 136 + ct * 16 + lo] = f2b(v);
        }
      }
    }
    bf16x8 a3[2][4];
    #pragma unroll
    for (int s = 0; s < 2; ++s)
      #pragma unroll
      for (int ks = 0; ks < 4; ++ks)
        a3[s][ks] = *(const bf16x8*)&fs[(size_t)(w * 32 + s * 16 + lo) * 136 + ks * 32 + g * 8];
    #pragma unroll
    for (int ks = 0; ks < 4; ++ks) {
      #pragma unroll
      for (int ct = 0; ct < 8; ++ct) {
        bf16x8 bw = *(const bf16x8*)&W2b[(size_t)(ct * 16 + lo) * 512 + fc * 128 + ks * 32 + g * 8];
        acc3[0][ct] = MFMA16(a3[0][ks], bw, acc3[0][ct]);
        acc3[1][ct] = MFMA16(a3[1][ks], bw, acc3[1][ct]);
      }
    }
  }

  // ---------------- epilogue: stage h2 tile in LDS, coalesced transposed write
  __syncthreads();
  #pragma unroll
  for (int s = 0; s < 2; ++s)
    #pragma unroll
    for (int ct = 0; ct < 8; ++ct) {
      float vals[4] = {acc3[s][ct].x, acc3[s][ct].y, acc3[s][ct].z, acc3[s][ct].w};
      #pragma unroll
      for (int r = 0; r < 4; ++r)
        h2s[(size_t)(w * 32 + s * 16 + g * 4 + r) * 132 + ct * 16 + lo] = vals[r];
    }
  __syncthreads();
  {
    int d = tid >> 1, half = tid & 1;
    #pragma unroll
    for (int j = 0; j < 16; ++j) {
      int nl = half * 64 + j * 4;
      int n = blockIdx.x * 128 + nl;
      if (n < NN) {
        float4 v;
        v.x = h2s[(size_t)(nl + 0) * 132 + d];
        v.y = h2s[(size_t)(nl + 1) * 132 + d];
        v.z = h2s[(size_t)(nl + 2) * 132 + d];
        v.w = h2s[(size_t)(nl + 3) * 132 + d];
        *(float4*)&h2T[((size_t)(b * 128 + d)) * NN + n] = v;
      }
    }
  }
}

// ---------------------------------------------------------------- K5: glimpse MHA (bf16 sp + bf16 stage tiles -> ~64 KB LDS)
__global__ __launch_bounds__(256, 1) void k_glimpse(
    const float* __restrict__ memory, const float* __restrict__ h2T,
    const float* __restrict__ ctx, const float* __restrict__ WmT,
    const float* __restrict__ W_mem, const float* __restrict__ b_mem,
    const float* __restrict__ W_gl, const float* __restrict__ b_gl,
    float* __restrict__ gq_out, float* __restrict__ ulog_out,
    float* __restrict__ c_out) {
  int b = blockIdx.x, tid = threadIdx.x;
  __shared__ float qarr[128];
  __shared__ float wql[1024];
  __shared__ float qb[8];
  __shared__ u16  spb[8 * NN];        // probs bf16 (16 KB)
  __shared__ float denom[8];
  __shared__ u16  hsmb[128 * 74];     // h2T tile bf16 (18.9 KB), stride 74
  __shared__ u16  msmb[128 * 74];     // memory tile bf16
  __shared__ float tl[1024];
  __shared__ float ul[128];
  __shared__ float gol[128];
  __shared__ float gqs[128];

  if (tid < 128) qarr[tid] = ctx[b * 128 + tid];
  __syncthreads();
  for (int idx = tid; idx < 1024; idx += 256) {
    int hh = idx >> 7, e = idx & 127;
    float acc = 0.0f;
    #pragma unroll
    for (int j = 0; j < 16; ++j) acc += qarr[hh * 16 + j] * WmT[(size_t)e * 384 + hh * 16 + j];
    wql[idx] = acc;
  }
  if (tid < 8) {
    float acc = 0.0f;
    #pragma unroll
    for (int j = 0; j < 16; ++j) acc += qarr[tid * 16 + j] * b_mem[tid * 16 + j];
    qb[tid] = acc;
  }
  __syncthreads();
  // pass 1: scores (stored bf16 — scores O(1-10), safe)
  for (int n = tid; n < NN; n += 256) {
    float a8[8];
    #pragma unroll
    for (int hh = 0; hh < 8; ++hh) a8[hh] = qb[hh];
    const float* mcol = &memory[(size_t)b * 384 * NN + n];
    for (int rr = 0; rr < 128; ++rr) a8[rr >> 4] += qarr[rr] * mcol[(size_t)rr * NN];
    const float* hcol = &h2T[(size_t)b * 128 * NN + n];
    for (int e = 0; e < 128; ++e) {
      float hv = hcol[(size_t)e * NN];
      #pragma unroll
      for (int hh = 0; hh < 8; ++hh) a8[hh] += wql[hh * 128 + e] * hv;
    }
    #pragma unroll
    for (int hh = 0; hh < 8; ++hh) spb[hh * NN + n] = f2b(0.25f * a8[hh]);
  }
  __syncthreads();
  // softmax per head (bf16 probs + f32 denom of the ROUNDED probs for consistency)
  {
    int hh = tid >> 5, l32 = tid & 31;
    float mx = -1e30f;
    for (int n = l32; n < NN; n += 32) mx = fmaxf(mx, b2f(spb[hh * NN + n]));
    #pragma unroll
    for (int off = 16; off >= 1; off >>= 1) mx = fmaxf(mx, __shfl_xor(mx, off));
    float sm = 0.0f;
    for (int n = l32; n < NN; n += 32) {
      float p = __expf(b2f(spb[hh * NN + n]) - mx);
      u16 pb = f2b(p);
      spb[hh * NN + n] = pb;
      sm += b2f(pb);
    }
    #pragma unroll
    for (int off = 16; off >= 1; off >>= 1) sm += __shfl_xor(sm, off);
    if (l32 == 0) denom[hh] = sm;
  }
  __syncthreads();
  // pass 2: t[h][e] and u[j] (bf16 stage tiles, f32 accumulate)
  float tacc[4] = {0.f, 0.f, 0.f, 0.f};
  float uacc = 0.0f;
  int e = tid & 127, half = tid >> 7;
  const float2* h2T2 = (const float2*)h2T;
  const float2* mem2 = (const float2*)memory;
  for (int t = 0; t < 16; ++t) {
    int nb = t * 64;
    int nmax = (NN - nb < 64) ? (NN - nb) : 64;
    for (int idx = tid; idx < 4096; idx += 256) {
      int row = idx >> 5, c2 = idx & 31;
      int nn2 = nb + c2 * 2;
      float2 hv = make_float2(0.f, 0.f), mv = make_float2(0.f, 0.f);
      if (nn2 < NN) {
        hv = h2T2[(((size_t)b * 128 + row) * NN + nn2) >> 1];
        mv = mem2[(((size_t)b * 384 + 128 + row) * NN + nn2) >> 1];
      }
      ushort2 hp, mp;
      hp.x = f2b(hv.x); hp.y = f2b(hv.y);
      mp.x = f2b(mv.x); mp.y = f2b(mv.y);
      *(ushort2*)&hsmb[row * 74 + c2 * 2] = hp;
      *(ushort2*)&msmb[row * 74 + c2 * 2] = mp;
    }
    __syncthreads();
    for (int nn = 0; nn < nmax; ++nn) {
      float hv = b2f(hsmb[e * 74 + nn]);
      #pragma unroll
      for (int hh2 = 0; hh2 < 4; ++hh2)
        tacc[hh2] += b2f(spb[(half * 4 + hh2) * NN + nb + nn]) * hv;
    }
    if (tid < 128) {
      int j = tid, hj = j >> 4;
      for (int nn = 0; nn < nmax; ++nn)
        uacc += b2f(spb[hj * NN + nb + nn]) * b2f(msmb[j * 74 + nn]);
    }
    __syncthreads();
  }
  #pragma unroll
  for (int hh2 = 0; hh2 < 4; ++hh2) tl[(half * 4 + hh2) * 128 + e] = tacc[hh2];
  if (tid < 128) ul[tid] = uacc;
  __syncthreads();
  if (tid < 128) {
    int j = tid, hj = j >> 4;
    float acc = ul[j];
    const float* wrow = &W_mem[(size_t)(128 + j) * 128];
    for (int e2 = 0; e2 < 128; ++e2) acc += wrow[e2] * tl[hj * 128 + e2];
    gol[j] = acc / denom[hj] + b_mem[128 + j];
  }
  __syncthreads();
  if (tid < 128) {
    int d = tid;
    float acc = b_gl[d];
    const float* wrow = &W_gl[(size_t)d * 128];
    for (int j = 0; j < 128; ++j) acc += wrow[j] * gol[j];
    gqs[d] = acc;
    gq_out[b * 128 + d] = acc;
  }
  __syncthreads();
  if (tid < 128) {
    int e2 = tid;
    float acc = 0.0f;
    for (int dd = 0; dd < 128; ++dd) acc += WmT[(size_t)e2 * 384 + 256 + dd] * gqs[dd];
    ulog_out[b * 128 + e2] = acc;
  } else if (tid == 128) {
    float acc = 0.0f;
    for (int dd = 0; dd < 128; ++dd) acc += b_mem[256 + dd] * gqs[dd];
    c_out[b] = acc;
  }
}

// ---------------------------------------------------------------- K6: logits + log_softmax
__global__ __launch_bounds__(256) void k_logits(
    const float* __restrict__ memory, const float* __restrict__ h2T,
    const float* __restrict__ gq, const float* __restrict__ ulog,
    const float* __restrict__ cbuf, const float* __restrict__ mask,
    float* __restrict__ out) {
  int b = blockIdx.x, tid = threadIdx.x;
  __shared__ float gql[128], ull[128];
  __shared__ float lg[NN];
  __shared__ float red[256];
  if (tid < 128) { gql[tid] = gq[b * 128 + tid]; ull[tid] = ulog[b * 128 + tid]; }
  __syncthreads();
  float cb = cbuf[b];
  float lmax = -1e30f;
  for (int n = tid; n < NN; n += 256) {
    float a1 = 0.0f, a2 = 0.0f;
    const float* mcol = &memory[((size_t)b * 384 + 256) * NN + n];
    const float* hcol = &h2T[(size_t)b * 128 * NN + n];
    for (int r = 0; r < 128; ++r) {
      a1 += mcol[(size_t)r * NN] * gql[r];
      a2 += hcol[(size_t)r * NN] * ull[r];
    }
    float z = (a1 + a2 + cb) * 0.088388347648318447f;
    float lv = tanhf(z) * CLIPV + logf(mask[(size_t)b * NN + n]);
    lg[n] = lv;
    lmax = fmaxf(lmax, lv);
  }
  red[tid] = lmax; __syncthreads();
  for (int s2 = 128; s2 >= 1; s2 >>= 1) {
    if (tid < s2) red[tid] = fmaxf(red[tid], red[tid + s2]);
    __syncthreads();
  }
  float mm = red[0];
  __syncthreads();
  float ls = 0.0f;
  for (int n = tid; n < NN; n += 256) ls += __expf(lg[n] - mm);
  red[tid] = ls; __syncthreads();
  for (int s2 = 128; s2 >= 1; s2 >>= 1) {
    if (tid < s2) red[tid] += red[tid + s2];
    __syncthreads();
  }
  float logS = logf(red[0]);
  __syncthreads();
  for (int n = tid; n < NN; n += 256) out[(size_t)b * NN + n] = lg[n] - mm - logS;
}

// ---------------------------------------------------------------- launch
extern "C" void kernel_launch(void* const* d_in, const int* in_sizes, int n_in,
                              void* d_out, int out_size, void* d_ws, size_t ws_size,
                              hipStream_t stream) {
  (void)in_sizes; (void)n_in; (void)out_size; (void)ws_size;
  const float* location = (const float*)d_in[0];
  const float* max_load = (const float*)d_in[1];
  const float* speed    = (const float*)d_in[2];
  const int*   next_agent = (const int*)d_in[3];
  const int*   position = (const int*)d_in[4];
  const float* tta      = (const float*)d_in[5];
  const float* load     = (const float*)d_in[6];
  const float* demand   = (const float*)d_in[7];
  const float* mask     = (const float*)d_in[8];
  const float* nef      = (const float*)d_in[9];
  const float* depot    = (const float*)d_in[10];
  const float* graph    = (const float*)d_in[11];
  const float* memory   = (const float*)d_in[12];
  const float* W_na     = (const float*)d_in[13];
  const float* b_na     = (const float*)d_in[14];
  const float* Wq       = (const float*)d_in[15];
  const float* bq       = (const float*)d_in[16];
  const float* Wk       = (const float*)d_in[17];
  const float* bk       = (const float*)d_in[18];
  const float* Wv       = (const float*)d_in[19];
  const float* bv       = (const float*)d_in[20];
  const float* Wo       = (const float*)d_in[21];
  const float* bo       = (const float*)d_in[22];
  const float* W_ff1    = (const float*)d_in[23];
  const float* b_ff1    = (const float*)d_in[24];
  const float* W_ff2    = (const float*)d_in[25];
  const float* b_ff2    = (const float*)d_in[26];
  const float* W_mem    = (const float*)d_in[27];
  const float* b_mem    = (const float*)d_in[28];
  const float* W_ctx    = (const float*)d_in[29];
  const float* b_ctx    = (const float*)d_in[30];
  const float* W_gl     = (const float*)d_in[31];
  const float* b_gl     = (const float*)d_in[32];

  float* p = (float*)d_ws;
  float* WmT = p;  p += 49152;
  u16*  Wqkvb = (u16*)p; p += 24576;
  u16*  Wob = (u16*)p;   p += 8192;
  u16*  W1b = (u16*)p;   p += 32768;
  u16*  W2b = (u16*)p;   p += 32768;
  float* ctx = p;  p += (size_t)BB * 128;
  float* gqb = p;  p += (size_t)BB * 128;
  float* ulb = p;  p += (size_t)BB * 128;
  float* cb  = p;  p += BB;
  u16*  h0b = (u16*)p;  p += (size_t)BB * NN * 64;    // bf16 [B,N,128]
  u16*  attnbH = (u16*)p; p += (size_t)BB * NN * 64;  // bf16 [B*H,N,16]
  u16*  Vh  = (u16*)p;  p += (size_t)BB * NN * 64;    // bf16 [B*H,N,16]
  float* h2t = p;  p += (size_t)BB * 128 * NN;
  // Qh/Kh alias h2t (dead before k_ff2 writes h2t)
  u16* Qh = (u16*)h2t;
  u16* Kh = (u16*)(h2t + (size_t)BB * NN * 64);

  hipLaunchKernelGGL(k_transpose, dim3(256), dim3(256), 0, stream,
                     Wo, W_ff1, W_ff2, W_mem, Wq, Wk, Wv, WmT, Wqkvb, Wob, W1b, W2b);
  hipLaunchKernelGGL(k_setup, dim3(BB), dim3(256), 0, stream,
                     location, max_load, speed, next_agent, position, load,
                     nef, depot, graph, W_ctx, b_ctx, ctx);
  hipLaunchKernelGGL(k_ne, dim3(63, BB), dim3(128), 0, stream,
                     location, next_agent, position, tta, load, demand, speed,
                     W_na, b_na, h0b);
  hipLaunchKernelGGL(k_qkv, dim3(16, BB), dim3(256), 0, stream,
                     h0b, Wqkvb, bq, bk, bv, Qh, Kh, Vh);
  hipLaunchKernelGGL(k_attn9, dim3(HH, BB), dim3(256), 0, stream,
                     Qh, Kh, Vh, attnbH);
  hipLaunchKernelGGL(k_ff2, dim3(8, BB), dim3(256), 0, stream,
                     h0b, attnbH, Wob, bo, W1b, b_ff1, W2b, b_ff2, h2t);
  hipLaunchKernelGGL(k_glimpse, dim3(BB), dim3(256), 0, stream,
                     memory, h2t, ctx, WmT, W_mem, b_mem, W_gl, b_gl, gqb, ulb, cb);
  hipLaunchKernelGGL(k_logits, dim3(BB), dim3(256), 0, stream,
                     memory, h2t, gqb, ulb, cb, mask, (float*)d_out);
}

// Round 17
// 1253.250 us; speedup vs baseline: 1.2640x; 1.2640x over previous
//
#include <hip/hip_runtime.h>
#include <math.h>

#define BB 256
#define AA 3
#define NN 1000
#define DD 128
#define HH 8
#define FFD 512
#define CLIPV 10.0f

typedef unsigned short u16;
typedef __attribute__((ext_vector_type(8))) short bf16x8;
typedef __attribute__((ext_vector_type(4))) float f32x4;

#define MFMA16(a, b, c) __builtin_amdgcn_mfma_f32_16x16x32_bf16(a, b, c, 0, 0, 0)

// fast exp2: bare v_exp_f32 (compiler handles transcendental hazards).
#if defined(__has_builtin)
#if __has_builtin(__builtin_amdgcn_exp2f)
#define EXP2(x) __builtin_amdgcn_exp2f(x)
#endif
#endif
#ifndef EXP2
#define EXP2(x) __expf((x) * 0.69314718055994531f)
#endif

__device__ __forceinline__ u16 f2b(float f) {
  union { float f; unsigned u; } v; v.f = f;
  unsigned r = (v.u + 0x7fffu + ((v.u >> 16) & 1u)) >> 16;
  return (u16)r;
}
__device__ __forceinline__ float b2f(u16 h) {
  union { float f; unsigned u; } v; v.u = ((unsigned)h) << 16;
  return v.f;
}
__device__ __forceinline__ unsigned cvtpk(float lo, float hi) {
  unsigned r;
  asm("v_cvt_pk_bf16_f32 %0, %1, %2" : "=v"(r) : "v"(lo), "v"(hi));
  return r;
}

// ---------------------------------------------------------------- K0: weight prep
__global__ __launch_bounds__(256) void k_transpose(
    const float* __restrict__ Wo, const float* __restrict__ W1,
    const float* __restrict__ W2, const float* __restrict__ Wm,
    const float* __restrict__ Wq, const float* __restrict__ Wk,
    const float* __restrict__ Wv,
    float* __restrict__ WmT, u16* __restrict__ Wqkvb,
    u16* __restrict__ Wob, u16* __restrict__ W1b, u16* __restrict__ W2b) {
  int idx = blockIdx.x * 256 + threadIdx.x;
  if (idx < 49152) { int e = idx / 384, r = idx % 384; WmT[idx] = Wm[r * 128 + e]; }
  if (idx < 49152) {
    int m = idx >> 14, rem = idx & 16383;
    const float* src = (m == 0) ? Wq : (m == 1) ? Wk : Wv;
    Wqkvb[idx] = f2b(src[rem]);
  }
  if (idx < 16384) Wob[idx] = f2b(Wo[idx]);
  if (idx < 65536) { W1b[idx] = f2b(W1[idx]); W2b[idx] = f2b(W2[idx]); }
}

// ---------------------------------------------------------------- K1: setup (context only)
__global__ __launch_bounds__(256) void k_setup(
    const float* __restrict__ location, const float* __restrict__ max_load,
    const float* __restrict__ speed, const int* __restrict__ next_agent,
    const int* __restrict__ position, const float* __restrict__ load,
    const float* __restrict__ nef, const float* __restrict__ depot,
    const float* __restrict__ graph, const float* __restrict__ W_ctx,
    const float* __restrict__ b_ctx, float* __restrict__ ctx_out) {
  int b = blockIdx.x;
  int tid = threadIdx.x;
  __shared__ float ai[131];
  int na = next_agent[b];
  if (tid < 128) {
    int ap = position[b * AA + na];
    ai[tid] = nef[((size_t)b * 128 + tid) * NN + ap];
  } else if (tid == 128) ai[128] = load[b * AA + na];
  else if (tid == 129) ai[129] = max_load[b * AA + na];
  else if (tid == 130) ai[130] = speed[b * AA + na];
  __syncthreads();
  if (tid < 128) {
    float acc = b_ctx[tid] + depot[b * 128 + tid] + graph[b * 128 + tid];
    for (int i = 0; i < 131; ++i) acc += W_ctx[tid * 131 + i] * ai[i];
    ctx_out[b * 128 + tid] = acc;
  }
}

// ---------------------------------------------------------------- K2: node features + embed -> h0b bf16 [B,N,128]
__global__ __launch_bounds__(128) void k_ne(
    const float* __restrict__ location, const int* __restrict__ next_agent,
    const int* __restrict__ position, const float* __restrict__ tta,
    const float* __restrict__ load, const float* __restrict__ demand,
    const float* __restrict__ speed, const float* __restrict__ W_na,
    const float* __restrict__ b_na, u16* __restrict__ h0b) {
  int tile = blockIdx.x, b = blockIdx.y, tid = threadIdx.x;
  __shared__ float nif[6][16];
  __shared__ int ordS[AA];
  __shared__ float alxS[AA], alyS[AA], spdS[AA], ttsS[AA], ldS[AA];
  if (tid == 0) {
    int na = next_agent[b];
    int c = 1; ordS[0] = na;
    for (int a = 0; a < AA; ++a) if (a != na) ordS[c++] = a;
    for (int s = 0; s < AA; ++s) {
      int g = ordS[s];
      int p = position[b * AA + g];
      alxS[s] = location[((size_t)b * NN + p) * 2];
      alyS[s] = location[((size_t)b * NN + p) * 2 + 1];
      spdS[s] = speed[b * AA + g];
      ttsS[s] = tta[b * AA + g];
      ldS[s]  = load[b * AA + g];
    }
  }
  __syncthreads();
  if (tid < 16) {
    int n = tile * 16 + tid;
    if (n < NN) {
      float lx = location[((size_t)b * NN + n) * 2];
      float ly = location[((size_t)b * NN + n) * 2 + 1];
      float dm = demand[(size_t)b * NN + n];
      #pragma unroll
      for (int s = 0; s < AA; ++s) {
        float dr = dm / ldS[s];
        if (dr > 1.0f) dr = -1.0f;
        if (dr != dr) dr = 0.0f;
        float dx = alxS[s] - lx, dy = alyS[s] - ly;
        float dist = sqrtf(dx * dx + dy * dy);
        float tt = (ttsS[s] == -1.0f) ? -1.0f : dist / spdS[s] + ttsS[s];
        nif[s][tid] = dr;
        nif[3 + s][tid] = tt;
      }
    } else {
      #pragma unroll
      for (int f = 0; f < 6; ++f) nif[f][tid] = 0.0f;
    }
  }
  __syncthreads();
  int d = tid;
  float w[6];
  #pragma unroll
  for (int i = 0; i < 6; ++i) w[i] = W_na[d * 6 + i];
  float bias = b_na[d];
  for (int i = 0; i < 16; ++i) {
    int n = tile * 16 + i;
    if (n >= NN) break;
    float acc = bias;
    #pragma unroll
    for (int f = 0; f < 6; ++f) acc += w[f] * nif[f][i];
    h0b[((size_t)b * NN + n) * 128 + d] = f2b(acc);
  }
}

// ---------------------------------------------------------------- K3: QKV projection (MFMA bf16) -> head-blocked Qh,Kh,Vh
__global__ __launch_bounds__(256, 2) void k_qkv(
    const u16* __restrict__ h0b, const u16* __restrict__ Wqkvb,
    const float* __restrict__ bq, const float* __restrict__ bk,
    const float* __restrict__ bv,
    u16* __restrict__ Qh, u16* __restrict__ Kh, u16* __restrict__ Vh) {
  int tile = blockIdx.x, b = blockIdx.y;
  int tid = threadIdx.x;
  int w = tid >> 6, l = tid & 63, lo = l & 15, g = l >> 4;
  int n0 = tile * 64 + w * 16;
  f32x4 acc[3][8];
  #pragma unroll
  for (int m = 0; m < 3; ++m)
    #pragma unroll
    for (int ct = 0; ct < 8; ++ct) acc[m][ct] = (f32x4){0.f, 0.f, 0.f, 0.f};

  for (int ks = 0; ks < 4; ++ks) {
    int n = n0 + lo; if (n > NN - 1) n = NN - 1;
    bf16x8 af = *(const bf16x8*)&h0b[((size_t)(b * NN + n)) * 128 + ks * 32 + g * 8];
    #pragma unroll
    for (int m = 0; m < 3; ++m) {
      #pragma unroll
      for (int ct = 0; ct < 8; ++ct) {
        bf16x8 bf_ = *(const bf16x8*)&Wqkvb[(size_t)m * 16384 + (ct * 16 + lo) * 128 + ks * 32 + g * 8];
        acc[m][ct] = MFMA16(af, bf_, acc[m][ct]);
      }
    }
  }
  const float* biases[3] = {bq, bk, bv};
  u16* outs[3] = {Qh, Kh, Vh};
  #pragma unroll
  for (int m = 0; m < 3; ++m) {
    float scale = (m == 0) ? 0.25f * 1.44269504088896f : 1.0f;
    #pragma unroll
    for (int ct = 0; ct < 8; ++ct) {      // ct == head index, lo == j within head
      int o = ct * 16 + lo;
      float bias = biases[m][o];
      float vals[4] = {acc[m][ct].x, acc[m][ct].y, acc[m][ct].z, acc[m][ct].w};
      #pragma unroll
      for (int r = 0; r < 4; ++r) {
        int n = n0 + g * 4 + r;
        if (n < NN)
          outs[m][((size_t)(b * HH + ct) * NN + n) * 16 + lo] = f2b((vals[r] + bias) * scale);
      }
    }
  }
}

// ---------------------------------------------------------------- K4: flash attention, max-free softmax + MFMA ones-denominator
__global__ __launch_bounds__(256, 4) void k_attn9(
    const u16* __restrict__ Qh, const u16* __restrict__ Kh,
    const u16* __restrict__ Vh, u16* __restrict__ attnbH) {
  __shared__ u16 Vt[16 * 1036];  // Vt[d][key], stride 1036 (518 words ≡ 6 mod 32): 0 conflicts
  int h = blockIdx.x, b = blockIdx.y;
  int bh = b * HH + h;
  const u16* Qp = Qh + (size_t)bh * NN * 16;
  const u16* Kp = Kh + (size_t)bh * NN * 16;
  const u16* Vp = Vh + (size_t)bh * NN * 16;
  int tid = threadIdx.x;
  {
    int half = tid & 1, kr = tid >> 1;
    for (int it = 0; it < 8; ++it) {
      int key = it * 128 + kr;
      int ksrc = key < NN ? key : NN - 1;
      union { uint4 q; u16 s[8]; } u;
      u.q = *(const uint4*)&Vp[(size_t)ksrc * 16 + half * 8];
      #pragma unroll
      for (int j = 0; j < 8; ++j) {
        u16 val = (key < NN) ? u.s[j] : (u16)0;
        Vt[(half * 8 + j) * 1036 + key] = val;
      }
    }
  }
  __syncthreads();

  int w = tid >> 6, l = tid & 63, lo = l & 15, g = l >> 4;
  const bf16x8 zfrag = {0, 0, 0, 0, 0, 0, 0, 0};
  const short one_b = (short)0x3F80;  // bf16 1.0
  const bf16x8 ones = {one_b, one_b, one_b, one_b, one_b, one_b, one_b, one_b};

  for (int tg = 0; tg < 4; ++tg) {
    int qbase = w * 256 + tg * 64;

    bf16x8 qf[4];
    #pragma unroll
    for (int t = 0; t < 4; ++t) {
      if (g < 2) {
        int q = qbase + t * 16 + lo; if (q > NN - 1) q = NN - 1;
        qf[t] = *(const bf16x8*)&Qp[(size_t)q * 16 + g * 8];
      } else qf[t] = zfrag;
    }

    f32x4 of[4], lacc[4];
    #pragma unroll
    for (int t = 0; t < 4; ++t) {
      of[t] = (f32x4){0.f, 0.f, 0.f, 0.f};
      lacc[t] = (f32x4){0.f, 0.f, 0.f, 0.f};
    }

    for (int c = 0; c < 16; ++c) {
      bf16x8 kf[4];
      #pragma unroll
      for (int kt = 0; kt < 4; ++kt) {
        if (g < 2) {
          int krow = c * 64 + kt * 16 + lo; if (krow > NN - 1) krow = NN - 1;
          kf[kt] = *(const bf16x8*)&Kp[(size_t)krow * 16 + g * 8];
        } else kf[kt] = zfrag;
      }
      bf16x8 vf[2];
      #pragma unroll
      for (int vt = 0; vt < 2; ++vt) {
        union { bf16x8 v; ushort4 h4[2]; } uu;
        int key0 = c * 64 + vt * 32 + g * 4;
        uu.h4[0] = *(const ushort4*)&Vt[lo * 1036 + key0];
        uu.h4[1] = *(const ushort4*)&Vt[lo * 1036 + key0 + 16];
        vf[vt] = uu.v;
      }
      #pragma unroll
      for (int t = 0; t < 4; ++t) {
        f32x4 sf[4];
        #pragma unroll
        for (int kt = 0; kt < 4; ++kt) {
          f32x4 zz = (f32x4){0.f, 0.f, 0.f, 0.f};
          sf[kt] = MFMA16(kf[kt], qf[t], zz);
        }
        float sc[16];
        #pragma unroll
        for (int kt = 0; kt < 4; ++kt) {
          sc[kt * 4 + 0] = sf[kt].x; sc[kt * 4 + 1] = sf[kt].y;
          sc[kt * 4 + 2] = sf[kt].z; sc[kt * 4 + 3] = sf[kt].w;
        }
        if (c == 15) {
          #pragma unroll
          for (int kt = 0; kt < 4; ++kt)
            #pragma unroll
            for (int r = 0; r < 4; ++r)
              if (960 + kt * 16 + g * 4 + r >= NN) sc[kt * 4 + r] = -1e30f;
        }
        float e[16];
        #pragma unroll
        for (int i = 0; i < 16; ++i) e[i] = EXP2(sc[i]);
        union { bf16x8 v; unsigned u[4]; } p0, p1;
        #pragma unroll
        for (int j = 0; j < 4; ++j) {
          p0.u[j] = cvtpk(e[2 * j], e[2 * j + 1]);
          p1.u[j] = cvtpk(e[8 + 2 * j], e[8 + 2 * j + 1]);
        }
        of[t] = MFMA16(vf[0], p0.v, of[t]);
        of[t] = MFMA16(vf[1], p1.v, of[t]);
        lacc[t] = MFMA16(ones, p0.v, lacc[t]);
        lacc[t] = MFMA16(ones, p1.v, lacc[t]);
      }
    }
    #pragma unroll
    for (int t = 0; t < 4; ++t) {
      float inv = 1.0f / lacc[t].x;
      int q = qbase + t * 16 + lo;
      if (q < NN) {
        union { ushort4 s; unsigned u[2]; } o4;
        o4.u[0] = cvtpk(of[t].x * inv, of[t].y * inv);
        o4.u[1] = cvtpk(of[t].z * inv, of[t].w * inv);
        *(ushort4*)&attnbH[((size_t)bh * NN + q) * 16 + g * 4] = o4.s;
      }
    }
  }
}

// ---------------------------------------------------------------- K_FF2: MFMA O-proj + residual + FF -> h2T [B,128,N]
// (256,2) bound: empirically optimal (379 us). Alternatives measured: low-pressure
// restructures 466/634 us; unbounded (unified VGPR+AGPR blowup -> 1 wave/SIMD) 699 us.
__global__ __launch_bounds__(256, 2) void k_ff2(
    const u16* __restrict__ h0b, const u16* __restrict__ attnbH,
    const u16* __restrict__ Wob, const float* __restrict__ bo,
    const u16* __restrict__ W1b, const float* __restrict__ b1,
    const u16* __restrict__ W2b, const float* __restrict__ b2,
    float* __restrict__ h2T) {
  __shared__ __align__(16) unsigned char smemraw[69632];
  u16* h1s = (u16*)smemraw;               // [4 waves][32 rows][136]
  u16* fs  = ((u16*)smemraw) + 4 * 32 * 136;
  float* h2s = (float*)smemraw;            // [128][132] (reused after sync)

  int b = blockIdx.y;
  int tid = threadIdx.x;
  int w = tid >> 6, l = tid & 63, lo = l & 15, g = l >> 4;
  int nb = blockIdx.x * 128 + w * 32;

  f32x4 acc3[2][8];

  float bo8[8], b28[8];
  #pragma unroll
  for (int ct = 0; ct < 8; ++ct) { bo8[ct] = bo[ct * 16 + lo]; b28[ct] = b2[ct * 16 + lo]; }

  // stage this wave's h0 tile (32 rows x 128) into fs via vector loads (wave-private)
  #pragma unroll
  for (int j = 0; j < 8; ++j) {
    int row = j * 4 + g;
    int n = nb + row; if (n > NN - 1) n = NN - 1;
    uint4 v = *(const uint4*)&h0b[((size_t)(b * NN + n)) * 128 + lo * 8];
    *(uint4*)&fs[(size_t)(w * 32 + row) * 136 + lo * 8] = v;
  }

  // ---------------- GEMM1: h1 = attn @ Wo^T + bo + h0 ; acc3 = h1 + b2
  #pragma unroll
  for (int s = 0; s < 2; ++s) {
    bf16x8 af[4];
    {
      int n = nb + s * 16 + lo; if (n > NN - 1) n = NN - 1;
      #pragma unroll
      for (int ks = 0; ks < 4; ++ks) {
        int hidx = ks * 2 + (g >> 1), j0 = (g & 1) * 8;
        af[ks] = *(const bf16x8*)&attnbH[((size_t)(b * HH + hidx) * NN + n) * 16 + j0];
      }
    }
    f32x4 a1[8];
    #pragma unroll
    for (int ct = 0; ct < 8; ++ct) a1[ct] = (f32x4){0.f, 0.f, 0.f, 0.f};
    #pragma unroll
    for (int ks = 0; ks < 4; ++ks) {
      #pragma unroll
      for (int ct = 0; ct < 8; ++ct) {
        bf16x8 bw = *(const bf16x8*)&Wob[(size_t)(ct * 16 + lo) * 128 + ks * 32 + g * 8];
        a1[ct] = MFMA16(af[ks], bw, a1[ct]);
      }
    }
    #pragma unroll
    for (int ct = 0; ct < 8; ++ct) {
      int d = ct * 16 + lo;
      float vals[4] = {a1[ct].x, a1[ct].y, a1[ct].z, a1[ct].w};
      #pragma unroll
      for (int r = 0; r < 4; ++r) {
        int lrow = s * 16 + g * 4 + r;
        float h0v = b2f(fs[(size_t)(w * 32 + lrow) * 136 + d]);
        float h1v = vals[r] + bo8[ct] + h0v;
        h1s[(size_t)(w * 32 + lrow) * 136 + d] = f2b(h1v);
        vals[r] = h1v + b28[ct];
      }
      acc3[s][ct] = (f32x4){vals[0], vals[1], vals[2], vals[3]};
    }
  }

  // ---------------- 4 chunks of 128 FF cols: GEMM2 (relu) + GEMM3 (accumulate)
  for (int fc = 0; fc < 4; ++fc) {
    bf16x8 a2[2][4];
    #pragma unroll
    for (int s = 0; s < 2; ++s)
      #pragma unroll
      for (int ks = 0; ks < 4; ++ks)
        a2[s][ks] = *(const bf16x8*)&h1s[(size_t)(w * 32 + s * 16 + lo) * 136 + ks * 32 + g * 8];
    f32x4 acc2[2][8];
    #pragma unroll
    for (int s = 0; s < 2; ++s)
      #pragma unroll
      for (int ct = 0; ct < 8; ++ct) acc2[s][ct] = (f32x4){0.f, 0.f, 0.f, 0.f};
    #pragma unroll
    for (int ks = 0; ks < 4; ++ks) {
      #pragma unroll
      for (int ct = 0; ct < 8; ++ct) {
        bf16x8 bw = *(const bf16x8*)&W1b[(size_t)(fc * 128 + ct * 16 + lo) * 128 + ks * 32 + g * 8];
        acc2[0][ct] = MFMA16(a2[0][ks], bw, acc2[0][ct]);
        acc2[1][ct] = MFMA16(a2[1][ks], bw, acc2[1][ct]);
      }
    }
    #pragma unroll
    for (int ct = 0; ct < 8; ++ct) {
      float b1f = b1[fc * 128 + ct * 16 + lo];
      #pragma unroll
      for (int s = 0; s < 2; ++s) {
        float vals[4] = {acc2[s][ct].x, acc2[s][ct].y, acc2[s][ct].z, acc2[s][ct].w};
        #pragma unroll
        for (int r = 0; r < 4; ++r) {
          float v = fmaxf(vals[r] + b1f, 0.0f);
          fs[(size_t)(w * 32 + s * 16 + g * 4 + r) * 136 + ct * 16 + lo] = f2b(v);
        }
      }
    }
    bf16x8 a3[2][4];
    #pragma unroll
    for (int s = 0; s < 2; ++s)
      #pragma unroll
      for (int ks = 0; ks < 4; ++ks)
        a3[s][ks] = *(const bf16x8*)&fs[(size_t)(w * 32 + s * 16 + lo) * 136 + ks * 32 + g * 8];
    #pragma unroll
    for (int ks = 0; ks < 4; ++ks) {
      #pragma unroll
      for (int ct = 0; ct < 8; ++ct) {
        bf16x8 bw = *(const bf16x8*)&W2b[(size_t)(ct * 16 + lo) * 512 + fc * 128 + ks * 32 + g * 8];
        acc3[0][ct] = MFMA16(a3[0][ks], bw, acc3[0][ct]);
        acc3[1][ct] = MFMA16(a3[1][ks], bw, acc3[1][ct]);
      }
    }
  }

  // ---------------- epilogue: stage h2 tile in LDS, coalesced transposed write
  __syncthreads();
  #pragma unroll
  for (int s = 0; s < 2; ++s)
    #pragma unroll
    for (int ct = 0; ct < 8; ++ct) {
      float vals[4] = {acc3[s][ct].x, acc3[s][ct].y, acc3[s][ct].z, acc3[s][ct].w};
      #pragma unroll
      for (int r = 0; r < 4; ++r)
        h2s[(size_t)(w * 32 + s * 16 + g * 4 + r) * 132 + ct * 16 + lo] = vals[r];
    }
  __syncthreads();
  {
    int d = tid >> 1, half = tid & 1;
    #pragma unroll
    for (int j = 0; j < 16; ++j) {
      int nl = half * 64 + j * 4;
      int n = blockIdx.x * 128 + nl;
      if (n < NN) {
        float4 v;
        v.x = h2s[(size_t)(nl + 0) * 132 + d];
        v.y = h2s[(size_t)(nl + 1) * 132 + d];
        v.z = h2s[(size_t)(nl + 2) * 132 + d];
        v.w = h2s[(size_t)(nl + 3) * 132 + d];
        *(float4*)&h2T[((size_t)(b * 128 + d)) * NN + n] = v;
      }
    }
  }
}

// ---------------------------------------------------------------- K5: glimpse MHA + gq + ulog + c per batch (R5/R12 proven)
__global__ __launch_bounds__(256, 1) void k_glimpse(
    const float* __restrict__ memory, const float* __restrict__ h2T,
    const float* __restrict__ ctx, const float* __restrict__ WmT,
    const float* __restrict__ W_mem, const float* __restrict__ b_mem,
    const float* __restrict__ W_gl, const float* __restrict__ b_gl,
    float* __restrict__ gq_out, float* __restrict__ ulog_out,
    float* __restrict__ c_out) {
  int b = blockIdx.x, tid = threadIdx.x;
  __shared__ float qarr[128];
  __shared__ float wql[1024];
  __shared__ float qb[8];
  __shared__ float sp[8 * NN];
  __shared__ float denom[8];
  __shared__ float hsm[128 * 70];
  __shared__ float msm[128 * 70];
  __shared__ float tl[1024];
  __shared__ float ul[128];
  __shared__ float gol[128];
  __shared__ float gqs[128];

  if (tid < 128) qarr[tid] = ctx[b * 128 + tid];
  __syncthreads();
  for (int idx = tid; idx < 1024; idx += 256) {
    int hh = idx >> 7, e = idx & 127;
    float acc = 0.0f;
    #pragma unroll
    for (int j = 0; j < 16; ++j) acc += qarr[hh * 16 + j] * WmT[(size_t)e * 384 + hh * 16 + j];
    wql[idx] = acc;
  }
  if (tid < 8) {
    float acc = 0.0f;
    #pragma unroll
    for (int j = 0; j < 16; ++j) acc += qarr[tid * 16 + j] * b_mem[tid * 16 + j];
    qb[tid] = acc;
  }
  __syncthreads();
  for (int n = tid; n < NN; n += 256) {
    float a8[8];
    #pragma unroll
    for (int hh = 0; hh < 8; ++hh) a8[hh] = qb[hh];
    const float* mcol = &memory[(size_t)b * 384 * NN + n];
    for (int rr = 0; rr < 128; ++rr) a8[rr >> 4] += qarr[rr] * mcol[(size_t)rr * NN];
    const float* hcol = &h2T[(size_t)b * 128 * NN + n];
    for (int e = 0; e < 128; ++e) {
      float hv = hcol[(size_t)e * NN];
      #pragma unroll
      for (int hh = 0; hh < 8; ++hh) a8[hh] += wql[hh * 128 + e] * hv;
    }
    #pragma unroll
    for (int hh = 0; hh < 8; ++hh) sp[hh * NN + n] = 0.25f * a8[hh];
  }
  __syncthreads();
  {
    int hh = tid >> 5, l32 = tid & 31;
    float mx = -1e30f;
    for (int n = l32; n < NN; n += 32) mx = fmaxf(mx, sp[hh * NN + n]);
    #pragma unroll
    for (int off = 16; off >= 1; off >>= 1) mx = fmaxf(mx, __shfl_xor(mx, off));
    float sm = 0.0f;
    for (int n = l32; n < NN; n += 32) {
      float p = __expf(sp[hh * NN + n] - mx);
      sp[hh * NN + n] = p; sm += p;
    }
    #pragma unroll
    for (int off = 16; off >= 1; off >>= 1) sm += __shfl_xor(sm, off);
    if (l32 == 0) denom[hh] = sm;
  }
  __syncthreads();
  float tacc[4] = {0.f, 0.f, 0.f, 0.f};
  float uacc = 0.0f;
  int e = tid & 127, half = tid >> 7;
  const float2* h2T2 = (const float2*)h2T;
  const float2* mem2 = (const float2*)memory;
  for (int t = 0; t < 16; ++t) {
    int nb = t * 64;
    int nmax = (NN - nb < 64) ? (NN - nb) : 64;
    for (int idx = tid; idx < 4096; idx += 256) {
      int row = idx >> 5, c2 = idx & 31;
      int nn2 = nb + c2 * 2;
      float2 hv = make_float2(0.f, 0.f), mv = make_float2(0.f, 0.f);
      if (nn2 < NN) {
        hv = h2T2[(((size_t)b * 128 + row) * NN + nn2) >> 1];
        mv = mem2[(((size_t)b * 384 + 128 + row) * NN + nn2) >> 1];
      }
      *(float2*)&hsm[row * 70 + c2 * 2] = hv;
      *(float2*)&msm[row * 70 + c2 * 2] = mv;
    }
    __syncthreads();
    for (int nn = 0; nn < nmax; ++nn) {
      float hv = hsm[e * 70 + nn];
      #pragma unroll
      for (int hh2 = 0; hh2 < 4; ++hh2)
        tacc[hh2] += sp[(half * 4 + hh2) * NN + nb + nn] * hv;
    }
    if (tid < 128) {
      int j = tid, hj = j >> 4;
      for (int nn = 0; nn < nmax; ++nn)
        uacc += sp[hj * NN + nb + nn] * msm[j * 70 + nn];
    }
    __syncthreads();
  }
  #pragma unroll
  for (int hh2 = 0; hh2 < 4; ++hh2) tl[(half * 4 + hh2) * 128 + e] = tacc[hh2];
  if (tid < 128) ul[tid] = uacc;
  __syncthreads();
  if (tid < 128) {
    int j = tid, hj = j >> 4;
    float acc = ul[j];
    const float* wrow = &W_mem[(size_t)(128 + j) * 128];
    for (int e2 = 0; e2 < 128; ++e2) acc += wrow[e2] * tl[hj * 128 + e2];
    gol[j] = acc / denom[hj] + b_mem[128 + j];
  }
  __syncthreads();
  if (tid < 128) {
    int d = tid;
    float acc = b_gl[d];
    const float* wrow = &W_gl[(size_t)d * 128];
    for (int j = 0; j < 128; ++j) acc += wrow[j] * gol[j];
    gqs[d] = acc;
    gq_out[b * 128 + d] = acc;
  }
  __syncthreads();
  if (tid < 128) {
    int e2 = tid;
    float acc = 0.0f;
    for (int dd = 0; dd < 128; ++dd) acc += WmT[(size_t)e2 * 384 + 256 + dd] * gqs[dd];
    ulog_out[b * 128 + e2] = acc;
  } else if (tid == 128) {
    float acc = 0.0f;
    for (int dd = 0; dd < 128; ++dd) acc += b_mem[256 + dd] * gqs[dd];
    c_out[b] = acc;
  }
}

// ---------------------------------------------------------------- K6: logits + log_softmax
__global__ __launch_bounds__(256) void k_logits(
    const float* __restrict__ memory, const float* __restrict__ h2T,
    const float* __restrict__ gq, const float* __restrict__ ulog,
    const float* __restrict__ cbuf, const float* __restrict__ mask,
    float* __restrict__ out) {
  int b = blockIdx.x, tid = threadIdx.x;
  __shared__ float gql[128], ull[128];
  __shared__ float lg[NN];
  __shared__ float red[256];
  if (tid < 128) { gql[tid] = gq[b * 128 + tid]; ull[tid] = ulog[b * 128 + tid]; }
  __syncthreads();
  float cb = cbuf[b];
  float lmax = -1e30f;
  for (int n = tid; n < NN; n += 256) {
    float a1 = 0.0f, a2 = 0.0f;
    const float* mcol = &memory[((size_t)b * 384 + 256) * NN + n];
    const float* hcol = &h2T[(size_t)b * 128 * NN + n];
    for (int r = 0; r < 128; ++r) {
      a1 += mcol[(size_t)r * NN] * gql[r];
      a2 += hcol[(size_t)r * NN] * ull[r];
    }
    float z = (a1 + a2 + cb) * 0.088388347648318447f;
    float lv = tanhf(z) * CLIPV + logf(mask[(size_t)b * NN + n]);
    lg[n] = lv;
    lmax = fmaxf(lmax, lv);
  }
  red[tid] = lmax; __syncthreads();
  for (int s2 = 128; s2 >= 1; s2 >>= 1) {
    if (tid < s2) red[tid] = fmaxf(red[tid], red[tid + s2]);
    __syncthreads();
  }
  float mm = red[0];
  __syncthreads();
  float ls = 0.0f;
  for (int n = tid; n < NN; n += 256) ls += __expf(lg[n] - mm);
  red[tid] = ls; __syncthreads();
  for (int s2 = 128; s2 >= 1; s2 >>= 1) {
    if (tid < s2) red[tid] += red[tid + s2];
    __syncthreads();
  }
  float logS = logf(red[0]);
  __syncthreads();
  for (int n = tid; n < NN; n += 256) out[(size_t)b * NN + n] = lg[n] - mm - logS;
}

// ---------------------------------------------------------------- launch
extern "C" void kernel_launch(void* const* d_in, const int* in_sizes, int n_in,
                              void* d_out, int out_size, void* d_ws, size_t ws_size,
                              hipStream_t stream) {
  (void)in_sizes; (void)n_in; (void)out_size; (void)ws_size;
  const float* location = (const float*)d_in[0];
  const float* max_load = (const float*)d_in[1];
  const float* speed    = (const float*)d_in[2];
  const int*   next_agent = (const int*)d_in[3];
  const int*   position = (const int*)d_in[4];
  const float* tta      = (const float*)d_in[5];
  const float* load     = (const float*)d_in[6];
  const float* demand   = (const float*)d_in[7];
  const float* mask     = (const float*)d_in[8];
  const float* nef      = (const float*)d_in[9];
  const float* depot    = (const float*)d_in[10];
  const float* graph    = (const float*)d_in[11];
  const float* memory   = (const float*)d_in[12];
  const float* W_na     = (const float*)d_in[13];
  const float* b_na     = (const float*)d_in[14];
  const float* Wq       = (const float*)d_in[15];
  const float* bq       = (const float*)d_in[16];
  const float* Wk       = (const float*)d_in[17];
  const float* bk       = (const float*)d_in[18];
  const float* Wv       = (const float*)d_in[19];
  const float* bv       = (const float*)d_in[20];
  const float* Wo       = (const float*)d_in[21];
  const float* bo       = (const float*)d_in[22];
  const float* W_ff1    = (const float*)d_in[23];
  const float* b_ff1    = (const float*)d_in[24];
  const float* W_ff2    = (const float*)d_in[25];
  const float* b_ff2    = (const float*)d_in[26];
  const float* W_mem    = (const float*)d_in[27];
  const float* b_mem    = (const float*)d_in[28];
  const float* W_ctx    = (const float*)d_in[29];
  const float* b_ctx    = (const float*)d_in[30];
  const float* W_gl     = (const float*)d_in[31];
  const float* b_gl     = (const float*)d_in[32];

  float* p = (float*)d_ws;
  float* WmT = p;  p += 49152;
  u16*  Wqkvb = (u16*)p; p += 24576;
  u16*  Wob = (u16*)p;   p += 8192;
  u16*  W1b = (u16*)p;   p += 32768;
  u16*  W2b = (u16*)p;   p += 32768;
  float* ctx = p;  p += (size_t)BB * 128;
  float* gqb = p;  p += (size_t)BB * 128;
  float* ulb = p;  p += (size_t)BB * 128;
  float* cb  = p;  p += BB;
  u16*  h0b = (u16*)p;  p += (size_t)BB * NN * 64;    // bf16 [B,N,128]
  u16*  attnbH = (u16*)p; p += (size_t)BB * NN * 64;  // bf16 [B*H,N,16]
  u16*  Vh  = (u16*)p;  p += (size_t)BB * NN * 64;    // bf16 [B*H,N,16]
  float* h2t = p;  p += (size_t)BB * 128 * NN;
  // Qh/Kh alias h2t (dead before k_ff2 writes h2t)
  u16* Qh = (u16*)h2t;
  u16* Kh = (u16*)(h2t + (size_t)BB * NN * 64);

  hipLaunchKernelGGL(k_transpose, dim3(256), dim3(256), 0, stream,
                     Wo, W_ff1, W_ff2, W_mem, Wq, Wk, Wv, WmT, Wqkvb, Wob, W1b, W2b);
  hipLaunchKernelGGL(k_setup, dim3(BB), dim3(256), 0, stream,
                     location, max_load, speed, next_agent, position, load,
                     nef, depot, graph, W_ctx, b_ctx, ctx);
  hipLaunchKernelGGL(k_ne, dim3(63, BB), dim3(128), 0, stream,
                     location, next_agent, position, tta, load, demand, speed,
                     W_na, b_na, h0b);
  hipLaunchKernelGGL(k_qkv, dim3(16, BB), dim3(256), 0, stream,
                     h0b, Wqkvb, bq, bk, bv, Qh, Kh, Vh);
  hipLaunchKernelGGL(k_attn9, dim3(HH, BB), dim3(256), 0, stream,
                     Qh, Kh, Vh, attnbH);
  hipLaunchKernelGGL(k_ff2, dim3(8, BB), dim3(256), 0, stream,
                     h0b, attnbH, Wob, bo, W1b, b_ff1, W2b, b_ff2, h2t);
  hipLaunchKernelGGL(k_glimpse, dim3(BB), dim3(256), 0, stream,
                     memory, h2t, ctx, WmT, W_mem, b_mem, W_gl, b_gl, gqb, ulb, cb);
  hipLaunchKernelGGL(k_logits, dim3(BB), dim3(256), 0, stream,
                     memory, h2t, gqb, ulb, cb, mask, (float*)d_out);
}

// Round 18
// 1251.205 us; speedup vs baseline: 1.2661x; 1.0016x over previous
//
#include <hip/hip_runtime.h>
#include <math.h>

#define BB 256
#define AA 3
#define NN 1000
#define DD 128
#define HH 8
#define FFD 512
#define CLIPV 10.0f

typedef unsigned short u16;
typedef __attribute__((ext_vector_type(8))) short bf16x8;
typedef __attribute__((ext_vector_type(4))) float f32x4;

#define MFMA16(a, b, c) __builtin_amdgcn_mfma_f32_16x16x32_bf16(a, b, c, 0, 0, 0)

// fast exp2: bare v_exp_f32 (compiler handles transcendental hazards).
#if defined(__has_builtin)
#if __has_builtin(__builtin_amdgcn_exp2f)
#define EXP2(x) __builtin_amdgcn_exp2f(x)
#endif
#endif
#ifndef EXP2
#define EXP2(x) __expf((x) * 0.69314718055994531f)
#endif

__device__ __forceinline__ u16 f2b(float f) {
  union { float f; unsigned u; } v; v.f = f;
  unsigned r = (v.u + 0x7fffu + ((v.u >> 16) & 1u)) >> 16;
  return (u16)r;
}
__device__ __forceinline__ float b2f(u16 h) {
  union { float f; unsigned u; } v; v.u = ((unsigned)h) << 16;
  return v.f;
}
__device__ __forceinline__ unsigned cvtpk(float lo, float hi) {
  unsigned r;
  asm("v_cvt_pk_bf16_f32 %0, %1, %2" : "=v"(r) : "v"(lo), "v"(hi));
  return r;
}

// ---------------------------------------------------------------- K0: weight prep
__global__ __launch_bounds__(256) void k_transpose(
    const float* __restrict__ Wo, const float* __restrict__ W1,
    const float* __restrict__ W2, const float* __restrict__ Wm,
    const float* __restrict__ Wq, const float* __restrict__ Wk,
    const float* __restrict__ Wv,
    float* __restrict__ WmT, u16* __restrict__ Wqkvb,
    u16* __restrict__ Wob, u16* __restrict__ W1b, u16* __restrict__ W2b) {
  int idx = blockIdx.x * 256 + threadIdx.x;
  if (idx < 49152) { int e = idx / 384, r = idx % 384; WmT[idx] = Wm[r * 128 + e]; }
  if (idx < 49152) {
    int m = idx >> 14, rem = idx & 16383;
    const float* src = (m == 0) ? Wq : (m == 1) ? Wk : Wv;
    Wqkvb[idx] = f2b(src[rem]);
  }
  if (idx < 16384) Wob[idx] = f2b(Wo[idx]);
  if (idx < 65536) { W1b[idx] = f2b(W1[idx]); W2b[idx] = f2b(W2[idx]); }
}

// ---------------------------------------------------------------- K1: setup (context only)
__global__ __launch_bounds__(256) void k_setup(
    const float* __restrict__ location, const float* __restrict__ max_load,
    const float* __restrict__ speed, const int* __restrict__ next_agent,
    const int* __restrict__ position, const float* __restrict__ load,
    const float* __restrict__ nef, const float* __restrict__ depot,
    const float* __restrict__ graph, const float* __restrict__ W_ctx,
    const float* __restrict__ b_ctx, float* __restrict__ ctx_out) {
  int b = blockIdx.x;
  int tid = threadIdx.x;
  __shared__ float ai[131];
  int na = next_agent[b];
  if (tid < 128) {
    int ap = position[b * AA + na];
    ai[tid] = nef[((size_t)b * 128 + tid) * NN + ap];
  } else if (tid == 128) ai[128] = load[b * AA + na];
  else if (tid == 129) ai[129] = max_load[b * AA + na];
  else if (tid == 130) ai[130] = speed[b * AA + na];
  __syncthreads();
  if (tid < 128) {
    float acc = b_ctx[tid] + depot[b * 128 + tid] + graph[b * 128 + tid];
    for (int i = 0; i < 131; ++i) acc += W_ctx[tid * 131 + i] * ai[i];
    ctx_out[b * 128 + tid] = acc;
  }
}

// ---------------------------------------------------------------- K2: node features + embed -> h0b bf16 [B,N,128]
__global__ __launch_bounds__(128) void k_ne(
    const float* __restrict__ location, const int* __restrict__ next_agent,
    const int* __restrict__ position, const float* __restrict__ tta,
    const float* __restrict__ load, const float* __restrict__ demand,
    const float* __restrict__ speed, const float* __restrict__ W_na,
    const float* __restrict__ b_na, u16* __restrict__ h0b) {
  int tile = blockIdx.x, b = blockIdx.y, tid = threadIdx.x;
  __shared__ float nif[6][16];
  __shared__ int ordS[AA];
  __shared__ float alxS[AA], alyS[AA], spdS[AA], ttsS[AA], ldS[AA];
  if (tid == 0) {
    int na = next_agent[b];
    int c = 1; ordS[0] = na;
    for (int a = 0; a < AA; ++a) if (a != na) ordS[c++] = a;
    for (int s = 0; s < AA; ++s) {
      int g = ordS[s];
      int p = position[b * AA + g];
      alxS[s] = location[((size_t)b * NN + p) * 2];
      alyS[s] = location[((size_t)b * NN + p) * 2 + 1];
      spdS[s] = speed[b * AA + g];
      ttsS[s] = tta[b * AA + g];
      ldS[s]  = load[b * AA + g];
    }
  }
  __syncthreads();
  if (tid < 16) {
    int n = tile * 16 + tid;
    if (n < NN) {
      float lx = location[((size_t)b * NN + n) * 2];
      float ly = location[((size_t)b * NN + n) * 2 + 1];
      float dm = demand[(size_t)b * NN + n];
      #pragma unroll
      for (int s = 0; s < AA; ++s) {
        float dr = dm / ldS[s];
        if (dr > 1.0f) dr = -1.0f;
        if (dr != dr) dr = 0.0f;
        float dx = alxS[s] - lx, dy = alyS[s] - ly;
        float dist = sqrtf(dx * dx + dy * dy);
        float tt = (ttsS[s] == -1.0f) ? -1.0f : dist / spdS[s] + ttsS[s];
        nif[s][tid] = dr;
        nif[3 + s][tid] = tt;
      }
    } else {
      #pragma unroll
      for (int f = 0; f < 6; ++f) nif[f][tid] = 0.0f;
    }
  }
  __syncthreads();
  int d = tid;
  float w[6];
  #pragma unroll
  for (int i = 0; i < 6; ++i) w[i] = W_na[d * 6 + i];
  float bias = b_na[d];
  for (int i = 0; i < 16; ++i) {
    int n = tile * 16 + i;
    if (n >= NN) break;
    float acc = bias;
    #pragma unroll
    for (int f = 0; f < 6; ++f) acc += w[f] * nif[f][i];
    h0b[((size_t)b * NN + n) * 128 + d] = f2b(acc);
  }
}

// ---------------------------------------------------------------- K3: QKV projection (MFMA bf16) -> head-blocked Qh,Kh,Vh
__global__ __launch_bounds__(256, 2) void k_qkv(
    const u16* __restrict__ h0b, const u16* __restrict__ Wqkvb,
    const float* __restrict__ bq, const float* __restrict__ bk,
    const float* __restrict__ bv,
    u16* __restrict__ Qh, u16* __restrict__ Kh, u16* __restrict__ Vh) {
  int tile = blockIdx.x, b = blockIdx.y;
  int tid = threadIdx.x;
  int w = tid >> 6, l = tid & 63, lo = l & 15, g = l >> 4;
  int n0 = tile * 64 + w * 16;
  f32x4 acc[3][8];
  #pragma unroll
  for (int m = 0; m < 3; ++m)
    #pragma unroll
    for (int ct = 0; ct < 8; ++ct) acc[m][ct] = (f32x4){0.f, 0.f, 0.f, 0.f};

  for (int ks = 0; ks < 4; ++ks) {
    int n = n0 + lo; if (n > NN - 1) n = NN - 1;
    bf16x8 af = *(const bf16x8*)&h0b[((size_t)(b * NN + n)) * 128 + ks * 32 + g * 8];
    #pragma unroll
    for (int m = 0; m < 3; ++m) {
      #pragma unroll
      for (int ct = 0; ct < 8; ++ct) {
        bf16x8 bf_ = *(const bf16x8*)&Wqkvb[(size_t)m * 16384 + (ct * 16 + lo) * 128 + ks * 32 + g * 8];
        acc[m][ct] = MFMA16(af, bf_, acc[m][ct]);
      }
    }
  }
  const float* biases[3] = {bq, bk, bv};
  u16* outs[3] = {Qh, Kh, Vh};
  #pragma unroll
  for (int m = 0; m < 3; ++m) {
    float scale = (m == 0) ? 0.25f * 1.44269504088896f : 1.0f;
    #pragma unroll
    for (int ct = 0; ct < 8; ++ct) {      // ct == head index, lo == j within head
      int o = ct * 16 + lo;
      float bias = biases[m][o];
      float vals[4] = {acc[m][ct].x, acc[m][ct].y, acc[m][ct].z, acc[m][ct].w};
      #pragma unroll
      for (int r = 0; r < 4; ++r) {
        int n = n0 + g * 4 + r;
        if (n < NN)
          outs[m][((size_t)(b * HH + ct) * NN + n) * 16 + lo] = f2b((vals[r] + bias) * scale);
      }
    }
  }
}

// ---------------------------------------------------------------- K4: flash attention, max-free softmax + MFMA ones-denominator
__global__ __launch_bounds__(256, 4) void k_attn9(
    const u16* __restrict__ Qh, const u16* __restrict__ Kh,
    const u16* __restrict__ Vh, u16* __restrict__ attnbH) {
  __shared__ u16 Vt[16 * 1036];  // Vt[d][key], stride 1036 (518 words ≡ 6 mod 32): 0 conflicts
  int h = blockIdx.x, b = blockIdx.y;
  int bh = b * HH + h;
  const u16* Qp = Qh + (size_t)bh * NN * 16;
  const u16* Kp = Kh + (size_t)bh * NN * 16;
  const u16* Vp = Vh + (size_t)bh * NN * 16;
  int tid = threadIdx.x;
  {
    int half = tid & 1, kr = tid >> 1;
    for (int it = 0; it < 8; ++it) {
      int key = it * 128 + kr;
      int ksrc = key < NN ? key : NN - 1;
      union { uint4 q; u16 s[8]; } u;
      u.q = *(const uint4*)&Vp[(size_t)ksrc * 16 + half * 8];
      #pragma unroll
      for (int j = 0; j < 8; ++j) {
        u16 val = (key < NN) ? u.s[j] : (u16)0;
        Vt[(half * 8 + j) * 1036 + key] = val;
      }
    }
  }
  __syncthreads();

  int w = tid >> 6, l = tid & 63, lo = l & 15, g = l >> 4;
  const bf16x8 zfrag = {0, 0, 0, 0, 0, 0, 0, 0};
  const short one_b = (short)0x3F80;  // bf16 1.0
  const bf16x8 ones = {one_b, one_b, one_b, one_b, one_b, one_b, one_b, one_b};

  for (int tg = 0; tg < 4; ++tg) {
    int qbase = w * 256 + tg * 64;

    bf16x8 qf[4];
    #pragma unroll
    for (int t = 0; t < 4; ++t) {
      if (g < 2) {
        int q = qbase + t * 16 + lo; if (q > NN - 1) q = NN - 1;
        qf[t] = *(const bf16x8*)&Qp[(size_t)q * 16 + g * 8];
      } else qf[t] = zfrag;
    }

    f32x4 of[4], lacc[4];
    #pragma unroll
    for (int t = 0; t < 4; ++t) {
      of[t] = (f32x4){0.f, 0.f, 0.f, 0.f};
      lacc[t] = (f32x4){0.f, 0.f, 0.f, 0.f};
    }

    for (int c = 0; c < 16; ++c) {
      bf16x8 kf[4];
      #pragma unroll
      for (int kt = 0; kt < 4; ++kt) {
        if (g < 2) {
          int krow = c * 64 + kt * 16 + lo; if (krow > NN - 1) krow = NN - 1;
          kf[kt] = *(const bf16x8*)&Kp[(size_t)krow * 16 + g * 8];
        } else kf[kt] = zfrag;
      }
      bf16x8 vf[2];
      #pragma unroll
      for (int vt = 0; vt < 2; ++vt) {
        union { bf16x8 v; ushort4 h4[2]; } uu;
        int key0 = c * 64 + vt * 32 + g * 4;
        uu.h4[0] = *(const ushort4*)&Vt[lo * 1036 + key0];
        uu.h4[1] = *(const ushort4*)&Vt[lo * 1036 + key0 + 16];
        vf[vt] = uu.v;
      }
      #pragma unroll
      for (int t = 0; t < 4; ++t) {
        f32x4 sf[4];
        #pragma unroll
        for (int kt = 0; kt < 4; ++kt) {
          f32x4 zz = (f32x4){0.f, 0.f, 0.f, 0.f};
          sf[kt] = MFMA16(kf[kt], qf[t], zz);
        }
        float sc[16];
        #pragma unroll
        for (int kt = 0; kt < 4; ++kt) {
          sc[kt * 4 + 0] = sf[kt].x; sc[kt * 4 + 1] = sf[kt].y;
          sc[kt * 4 + 2] = sf[kt].z; sc[kt * 4 + 3] = sf[kt].w;
        }
        if (c == 15) {
          #pragma unroll
          for (int kt = 0; kt < 4; ++kt)
            #pragma unroll
            for (int r = 0; r < 4; ++r)
              if (960 + kt * 16 + g * 4 + r >= NN) sc[kt * 4 + r] = -1e30f;
        }
        float e[16];
        #pragma unroll
        for (int i = 0; i < 16; ++i) e[i] = EXP2(sc[i]);
        union { bf16x8 v; unsigned u[4]; } p0, p1;
        #pragma unroll
        for (int j = 0; j < 4; ++j) {
          p0.u[j] = cvtpk(e[2 * j], e[2 * j + 1]);
          p1.u[j] = cvtpk(e[8 + 2 * j], e[8 + 2 * j + 1]);
        }
        of[t] = MFMA16(vf[0], p0.v, of[t]);
        of[t] = MFMA16(vf[1], p1.v, of[t]);
        lacc[t] = MFMA16(ones, p0.v, lacc[t]);
        lacc[t] = MFMA16(ones, p1.v, lacc[t]);
      }
    }
    #pragma unroll
    for (int t = 0; t < 4; ++t) {
      float inv = 1.0f / lacc[t].x;
      int q = qbase + t * 16 + lo;
      if (q < NN) {
        union { ushort4 s; unsigned u[2]; } o4;
        o4.u[0] = cvtpk(of[t].x * inv, of[t].y * inv);
        o4.u[1] = cvtpk(of[t].z * inv, of[t].w * inv);
        *(ushort4*)&attnbH[((size_t)bh * NN + q) * 16 + g * 4] = o4.s;
      }
    }
  }
}

// ---------------------------------------------------------------- K_FF2: MFMA O-proj + residual + FF -> h2T [B,128,N]
// (256,2) bound: empirically optimal (379 us). Alternatives measured: low-pressure
// restructures 466/634 us; unbounded (unified VGPR+AGPR blowup -> 1 wave/SIMD) 699 us.
__global__ __launch_bounds__(256, 2) void k_ff2(
    const u16* __restrict__ h0b, const u16* __restrict__ attnbH,
    const u16* __restrict__ Wob, const float* __restrict__ bo,
    const u16* __restrict__ W1b, const float* __restrict__ b1,
    const u16* __restrict__ W2b, const float* __restrict__ b2,
    float* __restrict__ h2T) {
  __shared__ __align__(16) unsigned char smemraw[69632];
  u16* h1s = (u16*)smemraw;               // [4 waves][32 rows][136]
  u16* fs  = ((u16*)smemraw) + 4 * 32 * 136;
  float* h2s = (float*)smemraw;            // [128][132] (reused after sync)

  int b = blockIdx.y;
  int tid = threadIdx.x;
  int w = tid >> 6, l = tid & 63, lo = l & 15, g = l >> 4;
  int nb = blockIdx.x * 128 + w * 32;

  f32x4 acc3[2][8];

  float bo8[8], b28[8];
  #pragma unroll
  for (int ct = 0; ct < 8; ++ct) { bo8[ct] = bo[ct * 16 + lo]; b28[ct] = b2[ct * 16 + lo]; }

  // stage this wave's h0 tile (32 rows x 128) into fs via vector loads (wave-private)
  #pragma unroll
  for (int j = 0; j < 8; ++j) {
    int row = j * 4 + g;
    int n = nb + row; if (n > NN - 1) n = NN - 1;
    uint4 v = *(const uint4*)&h0b[((size_t)(b * NN + n)) * 128 + lo * 8];
    *(uint4*)&fs[(size_t)(w * 32 + row) * 136 + lo * 8] = v;
  }

  // ---------------- GEMM1: h1 = attn @ Wo^T + bo + h0 ; acc3 = h1 + b2
  #pragma unroll
  for (int s = 0; s < 2; ++s) {
    bf16x8 af[4];
    {
      int n = nb + s * 16 + lo; if (n > NN - 1) n = NN - 1;
      #pragma unroll
      for (int ks = 0; ks < 4; ++ks) {
        int hidx = ks * 2 + (g >> 1), j0 = (g & 1) * 8;
        af[ks] = *(const bf16x8*)&attnbH[((size_t)(b * HH + hidx) * NN + n) * 16 + j0];
      }
    }
    f32x4 a1[8];
    #pragma unroll
    for (int ct = 0; ct < 8; ++ct) a1[ct] = (f32x4){0.f, 0.f, 0.f, 0.f};
    #pragma unroll
    for (int ks = 0; ks < 4; ++ks) {
      #pragma unroll
      for (int ct = 0; ct < 8; ++ct) {
        bf16x8 bw = *(const bf16x8*)&Wob[(size_t)(ct * 16 + lo) * 128 + ks * 32 + g * 8];
        a1[ct] = MFMA16(af[ks], bw, a1[ct]);
      }
    }
    #pragma unroll
    for (int ct = 0; ct < 8; ++ct) {
      int d = ct * 16 + lo;
      float vals[4] = {a1[ct].x, a1[ct].y, a1[ct].z, a1[ct].w};
      #pragma unroll
      for (int r = 0; r < 4; ++r) {
        int lrow = s * 16 + g * 4 + r;
        float h0v = b2f(fs[(size_t)(w * 32 + lrow) * 136 + d]);
        float h1v = vals[r] + bo8[ct] + h0v;
        h1s[(size_t)(w * 32 + lrow) * 136 + d] = f2b(h1v);
        vals[r] = h1v + b28[ct];
      }
      acc3[s][ct] = (f32x4){vals[0], vals[1], vals[2], vals[3]};
    }
  }

  // ---------------- 4 chunks of 128 FF cols: GEMM2 (relu) + GEMM3 (accumulate)
  for (int fc = 0; fc < 4; ++fc) {
    bf16x8 a2[2][4];
    #pragma unroll
    for (int s = 0; s < 2; ++s)
      #pragma unroll
      for (int ks = 0; ks < 4; ++ks)
        a2[s][ks] = *(const bf16x8*)&h1s[(size_t)(w * 32 + s * 16 + lo) * 136 + ks * 32 + g * 8];
    f32x4 acc2[2][8];
    #pragma unroll
    for (int s = 0; s < 2; ++s)
      #pragma unroll
      for (int ct = 0; ct < 8; ++ct) acc2[s][ct] = (f32x4){0.f, 0.f, 0.f, 0.f};
    #pragma unroll
    for (int ks = 0; ks < 4; ++ks) {
      #pragma unroll
      for (int ct = 0; ct < 8; ++ct) {
        bf16x8 bw = *(const bf16x8*)&W1b[(size_t)(fc * 128 + ct * 16 + lo) * 128 + ks * 32 + g * 8];
        acc2[0][ct] = MFMA16(a2[0][ks], bw, acc2[0][ct]);
        acc2[1][ct] = MFMA16(a2[1][ks], bw, acc2[1][ct]);
      }
    }
    #pragma unroll
    for (int ct = 0; ct < 8; ++ct) {
      float b1f = b1[fc * 128 + ct * 16 + lo];
      #pragma unroll
      for (int s = 0; s < 2; ++s) {
        float vals[4] = {acc2[s][ct].x, acc2[s][ct].y, acc2[s][ct].z, acc2[s][ct].w};
        #pragma unroll
        for (int r = 0; r < 4; ++r) {
          float v = fmaxf(vals[r] + b1f, 0.0f);
          fs[(size_t)(w * 32 + s * 16 + g * 4 + r) * 136 + ct * 16 + lo] = f2b(v);
        }
      }
    }
    bf16x8 a3[2][4];
    #pragma unroll
    for (int s = 0; s < 2; ++s)
      #pragma unroll
      for (int ks = 0; ks < 4; ++ks)
        a3[s][ks] = *(const bf16x8*)&fs[(size_t)(w * 32 + s * 16 + lo) * 136 + ks * 32 + g * 8];
    #pragma unroll
    for (int ks = 0; ks < 4; ++ks) {
      #pragma unroll
      for (int ct = 0; ct < 8; ++ct) {
        bf16x8 bw = *(const bf16x8*)&W2b[(size_t)(ct * 16 + lo) * 512 + fc * 128 + ks * 32 + g * 8];
        acc3[0][ct] = MFMA16(a3[0][ks], bw, acc3[0][ct]);
        acc3[1][ct] = MFMA16(a3[1][ks], bw, acc3[1][ct]);
      }
    }
  }

  // ---------------- epilogue: stage h2 tile in LDS, coalesced transposed write
  __syncthreads();
  #pragma unroll
  for (int s = 0; s < 2; ++s)
    #pragma unroll
    for (int ct = 0; ct < 8; ++ct) {
      float vals[4] = {acc3[s][ct].x, acc3[s][ct].y, acc3[s][ct].z, acc3[s][ct].w};
      #pragma unroll
      for (int r = 0; r < 4; ++r)
        h2s[(size_t)(w * 32 + s * 16 + g * 4 + r) * 132 + ct * 16 + lo] = vals[r];
    }
  __syncthreads();
  {
    int d = tid >> 1, half = tid & 1;
    #pragma unroll
    for (int j = 0; j < 16; ++j) {
      int nl = half * 64 + j * 4;
      int n = blockIdx.x * 128 + nl;
      if (n < NN) {
        float4 v;
        v.x = h2s[(size_t)(nl + 0) * 132 + d];
        v.y = h2s[(size_t)(nl + 1) * 132 + d];
        v.z = h2s[(size_t)(nl + 2) * 132 + d];
        v.w = h2s[(size_t)(nl + 3) * 132 + d];
        *(float4*)&h2T[((size_t)(b * 128 + d)) * NN + n] = v;
      }
    }
  }
}

// ---------------------------------------------------------------- K5: glimpse MHA + gq + ulog + c per batch (R5/R12 proven)
__global__ __launch_bounds__(256, 1) void k_glimpse(
    const float* __restrict__ memory, const float* __restrict__ h2T,
    const float* __restrict__ ctx, const float* __restrict__ WmT,
    const float* __restrict__ W_mem, const float* __restrict__ b_mem,
    const float* __restrict__ W_gl, const float* __restrict__ b_gl,
    float* __restrict__ gq_out, float* __restrict__ ulog_out,
    float* __restrict__ c_out) {
  int b = blockIdx.x, tid = threadIdx.x;
  __shared__ float qarr[128];
  __shared__ float wql[1024];
  __shared__ float qb[8];
  __shared__ float sp[8 * NN];
  __shared__ float denom[8];
  __shared__ float hsm[128 * 70];
  __shared__ float msm[128 * 70];
  __shared__ float tl[1024];
  __shared__ float ul[128];
  __shared__ float gol[128];
  __shared__ float gqs[128];

  if (tid < 128) qarr[tid] = ctx[b * 128 + tid];
  __syncthreads();
  for (int idx = tid; idx < 1024; idx += 256) {
    int hh = idx >> 7, e = idx & 127;
    float acc = 0.0f;
    #pragma unroll
    for (int j = 0; j < 16; ++j) acc += qarr[hh * 16 + j] * WmT[(size_t)e * 384 + hh * 16 + j];
    wql[idx] = acc;
  }
  if (tid < 8) {
    float acc = 0.0f;
    #pragma unroll
    for (int j = 0; j < 16; ++j) acc += qarr[tid * 16 + j] * b_mem[tid * 16 + j];
    qb[tid] = acc;
  }
  __syncthreads();
  for (int n = tid; n < NN; n += 256) {
    float a8[8];
    #pragma unroll
    for (int hh = 0; hh < 8; ++hh) a8[hh] = qb[hh];
    const float* mcol = &memory[(size_t)b * 384 * NN + n];
    for (int rr = 0; rr < 128; ++rr) a8[rr >> 4] += qarr[rr] * mcol[(size_t)rr * NN];
    const float* hcol = &h2T[(size_t)b * 128 * NN + n];
    for (int e = 0; e < 128; ++e) {
      float hv = hcol[(size_t)e * NN];
      #pragma unroll
      for (int hh = 0; hh < 8; ++hh) a8[hh] += wql[hh * 128 + e] * hv;
    }
    #pragma unroll
    for (int hh = 0; hh < 8; ++hh) sp[hh * NN + n] = 0.25f * a8[hh];
  }
  __syncthreads();
  {
    int hh = tid >> 5, l32 = tid & 31;
    float mx = -1e30f;
    for (int n = l32; n < NN; n += 32) mx = fmaxf(mx, sp[hh * NN + n]);
    #pragma unroll
    for (int off = 16; off >= 1; off >>= 1) mx = fmaxf(mx, __shfl_xor(mx, off));
    float sm = 0.0f;
    for (int n = l32; n < NN; n += 32) {
      float p = __expf(sp[hh * NN + n] - mx);
      sp[hh * NN + n] = p; sm += p;
    }
    #pragma unroll
    for (int off = 16; off >= 1; off >>= 1) sm += __shfl_xor(sm, off);
    if (l32 == 0) denom[hh] = sm;
  }
  __syncthreads();
  float tacc[4] = {0.f, 0.f, 0.f, 0.f};
  float uacc = 0.0f;
  int e = tid & 127, half = tid >> 7;
  const float2* h2T2 = (const float2*)h2T;
  const float2* mem2 = (const float2*)memory;
  for (int t = 0; t < 16; ++t) {
    int nb = t * 64;
    int nmax = (NN - nb < 64) ? (NN - nb) : 64;
    for (int idx = tid; idx < 4096; idx += 256) {
      int row = idx >> 5, c2 = idx & 31;
      int nn2 = nb + c2 * 2;
      float2 hv = make_float2(0.f, 0.f), mv = make_float2(0.f, 0.f);
      if (nn2 < NN) {
        hv = h2T2[(((size_t)b * 128 + row) * NN + nn2) >> 1];
        mv = mem2[(((size_t)b * 384 + 128 + row) * NN + nn2) >> 1];
      }
      *(float2*)&hsm[row * 70 + c2 * 2] = hv;
      *(float2*)&msm[row * 70 + c2 * 2] = mv;
    }
    __syncthreads();
    for (int nn = 0; nn < nmax; ++nn) {
      float hv = hsm[e * 70 + nn];
      #pragma unroll
      for (int hh2 = 0; hh2 < 4; ++hh2)
        tacc[hh2] += sp[(half * 4 + hh2) * NN + nb + nn] * hv;
    }
    if (tid < 128) {
      int j = tid, hj = j >> 4;
      for (int nn = 0; nn < nmax; ++nn)
        uacc += sp[hj * NN + nb + nn] * msm[j * 70 + nn];
    }
    __syncthreads();
  }
  #pragma unroll
  for (int hh2 = 0; hh2 < 4; ++hh2) tl[(half * 4 + hh2) * 128 + e] = tacc[hh2];
  if (tid < 128) ul[tid] = uacc;
  __syncthreads();
  if (tid < 128) {
    int j = tid, hj = j >> 4;
    float acc = ul[j];
    const float* wrow = &W_mem[(size_t)(128 + j) * 128];
    for (int e2 = 0; e2 < 128; ++e2) acc += wrow[e2] * tl[hj * 128 + e2];
    gol[j] = acc / denom[hj] + b_mem[128 + j];
  }
  __syncthreads();
  if (tid < 128) {
    int d = tid;
    float acc = b_gl[d];
    const float* wrow = &W_gl[(size_t)d * 128];
    for (int j = 0; j < 128; ++j) acc += wrow[j] * gol[j];
    gqs[d] = acc;
    gq_out[b * 128 + d] = acc;
  }
  __syncthreads();
  if (tid < 128) {
    int e2 = tid;
    float acc = 0.0f;
    for (int dd = 0; dd < 128; ++dd) acc += WmT[(size_t)e2 * 384 + 256 + dd] * gqs[dd];
    ulog_out[b * 128 + e2] = acc;
  } else if (tid == 128) {
    float acc = 0.0f;
    for (int dd = 0; dd < 128; ++dd) acc += b_mem[256 + dd] * gqs[dd];
    c_out[b] = acc;
  }
}

// ---------------------------------------------------------------- K6: logits + log_softmax
__global__ __launch_bounds__(256) void k_logits(
    const float* __restrict__ memory, const float* __restrict__ h2T,
    const float* __restrict__ gq, const float* __restrict__ ulog,
    const float* __restrict__ cbuf, const float* __restrict__ mask,
    float* __restrict__ out) {
  int b = blockIdx.x, tid = threadIdx.x;
  __shared__ float gql[128], ull[128];
  __shared__ float lg[NN];
  __shared__ float red[256];
  if (tid < 128) { gql[tid] = gq[b * 128 + tid]; ull[tid] = ulog[b * 128 + tid]; }
  __syncthreads();
  float cb = cbuf[b];
  float lmax = -1e30f;
  for (int n = tid; n < NN; n += 256) {
    float a1 = 0.0f, a2 = 0.0f;
    const float* mcol = &memory[((size_t)b * 384 + 256) * NN + n];
    const float* hcol = &h2T[(size_t)b * 128 * NN + n];
    for (int r = 0; r < 128; ++r) {
      a1 += mcol[(size_t)r * NN] * gql[r];
      a2 += hcol[(size_t)r * NN] * ull[r];
    }
    float z = (a1 + a2 + cb) * 0.088388347648318447f;
    float lv = tanhf(z) * CLIPV + logf(mask[(size_t)b * NN + n]);
    lg[n] = lv;
    lmax = fmaxf(lmax, lv);
  }
  red[tid] = lmax; __syncthreads();
  for (int s2 = 128; s2 >= 1; s2 >>= 1) {
    if (tid < s2) red[tid] = fmaxf(red[tid], red[tid + s2]);
    __syncthreads();
  }
  float mm = red[0];
  __syncthreads();
  float ls = 0.0f;
  for (int n = tid; n < NN; n += 256) ls += __expf(lg[n] - mm);
  red[tid] = ls; __syncthreads();
  for (int s2 = 128; s2 >= 1; s2 >>= 1) {
    if (tid < s2) red[tid] += red[tid + s2];
    __syncthreads();
  }
  float logS = logf(red[0]);
  __syncthreads();
  for (int n = tid; n < NN; n += 256) out[(size_t)b * NN + n] = lg[n] - mm - logS;
}

// ---------------------------------------------------------------- launch
extern "C" void kernel_launch(void* const* d_in, const int* in_sizes, int n_in,
                              void* d_out, int out_size, void* d_ws, size_t ws_size,
                              hipStream_t stream) {
  (void)in_sizes; (void)n_in; (void)out_size; (void)ws_size;
  const float* location = (const float*)d_in[0];
  const float* max_load = (const float*)d_in[1];
  const float* speed    = (const float*)d_in[2];
  const int*   next_agent = (const int*)d_in[3];
  const int*   position = (const int*)d_in[4];
  const float* tta      = (const float*)d_in[5];
  const float* load     = (const float*)d_in[6];
  const float* demand   = (const float*)d_in[7];
  const float* mask     = (const float*)d_in[8];
  const float* nef      = (const float*)d_in[9];
  const float* depot    = (const float*)d_in[10];
  const float* graph    = (const float*)d_in[11];
  const float* memory   = (const float*)d_in[12];
  const float* W_na     = (const float*)d_in[13];
  const float* b_na     = (const float*)d_in[14];
  const float* Wq       = (const float*)d_in[15];
  const float* bq       = (const float*)d_in[16];
  const float* Wk       = (const float*)d_in[17];
  const float* bk       = (const float*)d_in[18];
  const float* Wv       = (const float*)d_in[19];
  const float* bv       = (const float*)d_in[20];
  const float* Wo       = (const float*)d_in[21];
  const float* bo       = (const float*)d_in[22];
  const float* W_ff1    = (const float*)d_in[23];
  const float* b_ff1    = (const float*)d_in[24];
  const float* W_ff2    = (const float*)d_in[25];
  const float* b_ff2    = (const float*)d_in[26];
  const float* W_mem    = (const float*)d_in[27];
  const float* b_mem    = (const float*)d_in[28];
  const float* W_ctx    = (const float*)d_in[29];
  const float* b_ctx    = (const float*)d_in[30];
  const float* W_gl     = (const float*)d_in[31];
  const float* b_gl     = (const float*)d_in[32];

  float* p = (float*)d_ws;
  float* WmT = p;  p += 49152;
  u16*  Wqkvb = (u16*)p; p += 24576;
  u16*  Wob = (u16*)p;   p += 8192;
  u16*  W1b = (u16*)p;   p += 32768;
  u16*  W2b = (u16*)p;   p += 32768;
  float* ctx = p;  p += (size_t)BB * 128;
  float* gqb = p;  p += (size_t)BB * 128;
  float* ulb = p;  p += (size_t)BB * 128;
  float* cb  = p;  p += BB;
  u16*  h0b = (u16*)p;  p += (size_t)BB * NN * 64;    // bf16 [B,N,128]
  u16*  attnbH = (u16*)p; p += (size_t)BB * NN * 64;  // bf16 [B*H,N,16]
  u16*  Vh  = (u16*)p;  p += (size_t)BB * NN * 64;    // bf16 [B*H,N,16]
  float* h2t = p;  p += (size_t)BB * 128 * NN;
  // Qh/Kh alias h2t (dead before k_ff2 writes h2t)
  u16* Qh = (u16*)h2t;
  u16* Kh = (u16*)(h2t + (size_t)BB * NN * 64);

  hipLaunchKernelGGL(k_transpose, dim3(256), dim3(256), 0, stream,
                     Wo, W_ff1, W_ff2, W_mem, Wq, Wk, Wv, WmT, Wqkvb, Wob, W1b, W2b);
  hipLaunchKernelGGL(k_setup, dim3(BB), dim3(256), 0, stream,
                     location, max_load, speed, next_agent, position, load,
                     nef, depot, graph, W_ctx, b_ctx, ctx);
  hipLaunchKernelGGL(k_ne, dim3(63, BB), dim3(128), 0, stream,
                     location, next_agent, position, tta, load, demand, speed,
                     W_na, b_na, h0b);
  hipLaunchKernelGGL(k_qkv, dim3(16, BB), dim3(256), 0, stream,
                     h0b, Wqkvb, bq, bk, bv, Qh, Kh, Vh);
  hipLaunchKernelGGL(k_attn9, dim3(HH, BB), dim3(256), 0, stream,
                     Qh, Kh, Vh, attnbH);
  hipLaunchKernelGGL(k_ff2, dim3(8, BB), dim3(256), 0, stream,
                     h0b, attnbH, Wob, bo, W1b, b_ff1, W2b, b_ff2, h2t);
  hipLaunchKernelGGL(k_glimpse, dim3(BB), dim3(256), 0, stream,
                     memory, h2t, ctx, WmT, W_mem, b_mem, W_gl, b_gl, gqb, ulb, cb);
  hipLaunchKernelGGL(k_logits, dim3(BB), dim3(256), 0, stream,
                     memory, h2t, gqb, ulb, cb, mask, (float*)d_out);
}

// Round 19
// 1136.563 us; speedup vs baseline: 1.3938x; 1.1009x over previous
//
#include <hip/hip_runtime.h>
#include <math.h>

#define BB 256
#define AA 3
#define NN 1000
#define DD 128
#define HH 8
#define FFD 512
#define CLIPV 10.0f

typedef unsigned short u16;
typedef __attribute__((ext_vector_type(8))) short bf16x8;
typedef __attribute__((ext_vector_type(4))) float f32x4;

#define MFMA16(a, b, c) __builtin_amdgcn_mfma_f32_16x16x32_bf16(a, b, c, 0, 0, 0)

// fast exp2: bare v_exp_f32 (compiler handles transcendental hazards).
#if defined(__has_builtin)
#if __has_builtin(__builtin_amdgcn_exp2f)
#define EXP2(x) __builtin_amdgcn_exp2f(x)
#endif
#endif
#ifndef EXP2
#define EXP2(x) __expf((x) * 0.69314718055994531f)
#endif

__device__ __forceinline__ u16 f2b(float f) {
  union { float f; unsigned u; } v; v.f = f;
  unsigned r = (v.u + 0x7fffu + ((v.u >> 16) & 1u)) >> 16;
  return (u16)r;
}
__device__ __forceinline__ float b2f(u16 h) {
  union { float f; unsigned u; } v; v.u = ((unsigned)h) << 16;
  return v.f;
}
__device__ __forceinline__ unsigned cvtpk(float lo, float hi) {
  unsigned r;
  asm("v_cvt_pk_bf16_f32 %0, %1, %2" : "=v"(r) : "v"(lo), "v"(hi));
  return r;
}

// ---------------------------------------------------------------- K0: weight prep
__global__ __launch_bounds__(256) void k_transpose(
    const float* __restrict__ Wo, const float* __restrict__ W1,
    const float* __restrict__ W2, const float* __restrict__ Wm,
    const float* __restrict__ Wq, const float* __restrict__ Wk,
    const float* __restrict__ Wv,
    float* __restrict__ WmT, u16* __restrict__ Wqkvb,
    u16* __restrict__ Wob, u16* __restrict__ W1b, u16* __restrict__ W2b) {
  int idx = blockIdx.x * 256 + threadIdx.x;
  if (idx < 49152) { int e = idx / 384, r = idx % 384; WmT[idx] = Wm[r * 128 + e]; }
  if (idx < 49152) {
    int m = idx >> 14, rem = idx & 16383;
    const float* src = (m == 0) ? Wq : (m == 1) ? Wk : Wv;
    Wqkvb[idx] = f2b(src[rem]);
  }
  if (idx < 16384) Wob[idx] = f2b(Wo[idx]);
  if (idx < 65536) { W1b[idx] = f2b(W1[idx]); W2b[idx] = f2b(W2[idx]); }
}

// ---------------------------------------------------------------- K1: setup (context only)
__global__ __launch_bounds__(256) void k_setup(
    const float* __restrict__ location, const float* __restrict__ max_load,
    const float* __restrict__ speed, const int* __restrict__ next_agent,
    const int* __restrict__ position, const float* __restrict__ load,
    const float* __restrict__ nef, const float* __restrict__ depot,
    const float* __restrict__ graph, const float* __restrict__ W_ctx,
    const float* __restrict__ b_ctx, float* __restrict__ ctx_out) {
  int b = blockIdx.x;
  int tid = threadIdx.x;
  __shared__ float ai[131];
  int na = next_agent[b];
  if (tid < 128) {
    int ap = position[b * AA + na];
    ai[tid] = nef[((size_t)b * 128 + tid) * NN + ap];
  } else if (tid == 128) ai[128] = load[b * AA + na];
  else if (tid == 129) ai[129] = max_load[b * AA + na];
  else if (tid == 130) ai[130] = speed[b * AA + na];
  __syncthreads();
  if (tid < 128) {
    float acc = b_ctx[tid] + depot[b * 128 + tid] + graph[b * 128 + tid];
    for (int i = 0; i < 131; ++i) acc += W_ctx[tid * 131 + i] * ai[i];
    ctx_out[b * 128 + tid] = acc;
  }
}

// ---------------------------------------------------------------- K2: node features + embed -> h0b bf16 [B,N,128]
__global__ __launch_bounds__(128) void k_ne(
    const float* __restrict__ location, const int* __restrict__ next_agent,
    const int* __restrict__ position, const float* __restrict__ tta,
    const float* __restrict__ load, const float* __restrict__ demand,
    const float* __restrict__ speed, const float* __restrict__ W_na,
    const float* __restrict__ b_na, u16* __restrict__ h0b) {
  int tile = blockIdx.x, b = blockIdx.y, tid = threadIdx.x;
  __shared__ float nif[6][16];
  __shared__ int ordS[AA];
  __shared__ float alxS[AA], alyS[AA], spdS[AA], ttsS[AA], ldS[AA];
  if (tid == 0) {
    int na = next_agent[b];
    int c = 1; ordS[0] = na;
    for (int a = 0; a < AA; ++a) if (a != na) ordS[c++] = a;
    for (int s = 0; s < AA; ++s) {
      int g = ordS[s];
      int p = position[b * AA + g];
      alxS[s] = location[((size_t)b * NN + p) * 2];
      alyS[s] = location[((size_t)b * NN + p) * 2 + 1];
      spdS[s] = speed[b * AA + g];
      ttsS[s] = tta[b * AA + g];
      ldS[s]  = load[b * AA + g];
    }
  }
  __syncthreads();
  if (tid < 16) {
    int n = tile * 16 + tid;
    if (n < NN) {
      float lx = location[((size_t)b * NN + n) * 2];
      float ly = location[((size_t)b * NN + n) * 2 + 1];
      float dm = demand[(size_t)b * NN + n];
      #pragma unroll
      for (int s = 0; s < AA; ++s) {
        float dr = dm / ldS[s];
        if (dr > 1.0f) dr = -1.0f;
        if (dr != dr) dr = 0.0f;
        float dx = alxS[s] - lx, dy = alyS[s] - ly;
        float dist = sqrtf(dx * dx + dy * dy);
        float tt = (ttsS[s] == -1.0f) ? -1.0f : dist / spdS[s] + ttsS[s];
        nif[s][tid] = dr;
        nif[3 + s][tid] = tt;
      }
    } else {
      #pragma unroll
      for (int f = 0; f < 6; ++f) nif[f][tid] = 0.0f;
    }
  }
  __syncthreads();
  int d = tid;
  float w[6];
  #pragma unroll
  for (int i = 0; i < 6; ++i) w[i] = W_na[d * 6 + i];
  float bias = b_na[d];
  for (int i = 0; i < 16; ++i) {
    int n = tile * 16 + i;
    if (n >= NN) break;
    float acc = bias;
    #pragma unroll
    for (int f = 0; f < 6; ++f) acc += w[f] * nif[f][i];
    h0b[((size_t)b * NN + n) * 128 + d] = f2b(acc);
  }
}

// ---------------------------------------------------------------- K3: QKV projection (MFMA bf16) -> head-blocked Qh,Kh,Vh
__global__ __launch_bounds__(256, 2) void k_qkv(
    const u16* __restrict__ h0b, const u16* __restrict__ Wqkvb,
    const float* __restrict__ bq, const float* __restrict__ bk,
    const float* __restrict__ bv,
    u16* __restrict__ Qh, u16* __restrict__ Kh, u16* __restrict__ Vh) {
  int tile = blockIdx.x, b = blockIdx.y;
  int tid = threadIdx.x;
  int w = tid >> 6, l = tid & 63, lo = l & 15, g = l >> 4;
  int n0 = tile * 64 + w * 16;
  f32x4 acc[3][8];
  #pragma unroll
  for (int m = 0; m < 3; ++m)
    #pragma unroll
    for (int ct = 0; ct < 8; ++ct) acc[m][ct] = (f32x4){0.f, 0.f, 0.f, 0.f};

  for (int ks = 0; ks < 4; ++ks) {
    int n = n0 + lo; if (n > NN - 1) n = NN - 1;
    bf16x8 af = *(const bf16x8*)&h0b[((size_t)(b * NN + n)) * 128 + ks * 32 + g * 8];
    #pragma unroll
    for (int m = 0; m < 3; ++m) {
      #pragma unroll
      for (int ct = 0; ct < 8; ++ct) {
        bf16x8 bf_ = *(const bf16x8*)&Wqkvb[(size_t)m * 16384 + (ct * 16 + lo) * 128 + ks * 32 + g * 8];
        acc[m][ct] = MFMA16(af, bf_, acc[m][ct]);
      }
    }
  }
  const float* biases[3] = {bq, bk, bv};
  u16* outs[3] = {Qh, Kh, Vh};
  #pragma unroll
  for (int m = 0; m < 3; ++m) {
    float scale = (m == 0) ? 0.25f * 1.44269504088896f : 1.0f;
    #pragma unroll
    for (int ct = 0; ct < 8; ++ct) {      // ct == head index, lo == j within head
      int o = ct * 16 + lo;
      float bias = biases[m][o];
      float vals[4] = {acc[m][ct].x, acc[m][ct].y, acc[m][ct].z, acc[m][ct].w};
      #pragma unroll
      for (int r = 0; r < 4; ++r) {
        int n = n0 + g * 4 + r;
        if (n < NN)
          outs[m][((size_t)(b * HH + ct) * NN + n) * 16 + lo] = f2b((vals[r] + bias) * scale);
      }
    }
  }
}

// ---------------------------------------------------------------- K4: flash attention, max-free softmax + MFMA ones-denominator
__global__ __launch_bounds__(256, 4) void k_attn9(
    const u16* __restrict__ Qh, const u16* __restrict__ Kh,
    const u16* __restrict__ Vh, u16* __restrict__ attnbH) {
  __shared__ u16 Vt[16 * 1036];  // Vt[d][key], stride 1036 (518 words ≡ 6 mod 32): 0 conflicts
  int h = blockIdx.x, b = blockIdx.y;
  int bh = b * HH + h;
  const u16* Qp = Qh + (size_t)bh * NN * 16;
  const u16* Kp = Kh + (size_t)bh * NN * 16;
  const u16* Vp = Vh + (size_t)bh * NN * 16;
  int tid = threadIdx.x;
  {
    int half = tid & 1, kr = tid >> 1;
    for (int it = 0; it < 8; ++it) {
      int key = it * 128 + kr;
      int ksrc = key < NN ? key : NN - 1;
      union { uint4 q; u16 s[8]; } u;
      u.q = *(const uint4*)&Vp[(size_t)ksrc * 16 + half * 8];
      #pragma unroll
      for (int j = 0; j < 8; ++j) {
        u16 val = (key < NN) ? u.s[j] : (u16)0;
        Vt[(half * 8 + j) * 1036 + key] = val;
      }
    }
  }
  __syncthreads();

  int w = tid >> 6, l = tid & 63, lo = l & 15, g = l >> 4;
  const bf16x8 zfrag = {0, 0, 0, 0, 0, 0, 0, 0};
  const short one_b = (short)0x3F80;  // bf16 1.0
  const bf16x8 ones = {one_b, one_b, one_b, one_b, one_b, one_b, one_b, one_b};

  for (int tg = 0; tg < 4; ++tg) {
    int qbase = w * 256 + tg * 64;

    bf16x8 qf[4];
    #pragma unroll
    for (int t = 0; t < 4; ++t) {
      if (g < 2) {
        int q = qbase + t * 16 + lo; if (q > NN - 1) q = NN - 1;
        qf[t] = *(const bf16x8*)&Qp[(size_t)q * 16 + g * 8];
      } else qf[t] = zfrag;
    }

    f32x4 of[4], lacc[4];
    #pragma unroll
    for (int t = 0; t < 4; ++t) {
      of[t] = (f32x4){0.f, 0.f, 0.f, 0.f};
      lacc[t] = (f32x4){0.f, 0.f, 0.f, 0.f};
    }

    for (int c = 0; c < 16; ++c) {
      bf16x8 kf[4];
      #pragma unroll
      for (int kt = 0; kt < 4; ++kt) {
        if (g < 2) {
          int krow = c * 64 + kt * 16 + lo; if (krow > NN - 1) krow = NN - 1;
          kf[kt] = *(const bf16x8*)&Kp[(size_t)krow * 16 + g * 8];
        } else kf[kt] = zfrag;
      }
      bf16x8 vf[2];
      #pragma unroll
      for (int vt = 0; vt < 2; ++vt) {
        union { bf16x8 v; ushort4 h4[2]; } uu;
        int key0 = c * 64 + vt * 32 + g * 4;
        uu.h4[0] = *(const ushort4*)&Vt[lo * 1036 + key0];
        uu.h4[1] = *(const ushort4*)&Vt[lo * 1036 + key0 + 16];
        vf[vt] = uu.v;
      }
      #pragma unroll
      for (int t = 0; t < 4; ++t) {
        f32x4 sf[4];
        #pragma unroll
        for (int kt = 0; kt < 4; ++kt) {
          f32x4 zz = (f32x4){0.f, 0.f, 0.f, 0.f};
          sf[kt] = MFMA16(kf[kt], qf[t], zz);
        }
        float sc[16];
        #pragma unroll
        for (int kt = 0; kt < 4; ++kt) {
          sc[kt * 4 + 0] = sf[kt].x; sc[kt * 4 + 1] = sf[kt].y;
          sc[kt * 4 + 2] = sf[kt].z; sc[kt * 4 + 3] = sf[kt].w;
        }
        if (c == 15) {
          #pragma unroll
          for (int kt = 0; kt < 4; ++kt)
            #pragma unroll
            for (int r = 0; r < 4; ++r)
              if (960 + kt * 16 + g * 4 + r >= NN) sc[kt * 4 + r] = -1e30f;
        }
        float e[16];
        #pragma unroll
        for (int i = 0; i < 16; ++i) e[i] = EXP2(sc[i]);
        union { bf16x8 v; unsigned u[4]; } p0, p1;
        #pragma unroll
        for (int j = 0; j < 4; ++j) {
          p0.u[j] = cvtpk(e[2 * j], e[2 * j + 1]);
          p1.u[j] = cvtpk(e[8 + 2 * j], e[8 + 2 * j + 1]);
        }
        of[t] = MFMA16(vf[0], p0.v, of[t]);
        of[t] = MFMA16(vf[1], p1.v, of[t]);
        lacc[t] = MFMA16(ones, p0.v, lacc[t]);
        lacc[t] = MFMA16(ones, p1.v, lacc[t]);
      }
    }
    #pragma unroll
    for (int t = 0; t < 4; ++t) {
      float inv = 1.0f / lacc[t].x;
      int q = qbase + t * 16 + lo;
      if (q < NN) {
        union { ushort4 s; unsigned u[2]; } o4;
        o4.u[0] = cvtpk(of[t].x * inv, of[t].y * inv);
        o4.u[1] = cvtpk(of[t].z * inv, of[t].w * inv);
        *(ushort4*)&attnbH[((size_t)bh * NN + q) * 16 + g * 4] = o4.s;
      }
    }
  }
}

// ---------------------------------------------------------------- K_FF2: MFMA O-proj + residual + FF -> h2T [B,128,N]
// (256,2) bound: empirically optimal (379 us).
__global__ __launch_bounds__(256, 2) void k_ff2(
    const u16* __restrict__ h0b, const u16* __restrict__ attnbH,
    const u16* __restrict__ Wob, const float* __restrict__ bo,
    const u16* __restrict__ W1b, const float* __restrict__ b1,
    const u16* __restrict__ W2b, const float* __restrict__ b2,
    float* __restrict__ h2T) {
  __shared__ __align__(16) unsigned char smemraw[69632];
  u16* h1s = (u16*)smemraw;               // [4 waves][32 rows][136]
  u16* fs  = ((u16*)smemraw) + 4 * 32 * 136;
  float* h2s = (float*)smemraw;            // [128][132] (reused after sync)

  int b = blockIdx.y;
  int tid = threadIdx.x;
  int w = tid >> 6, l = tid & 63, lo = l & 15, g = l >> 4;
  int nb = blockIdx.x * 128 + w * 32;

  f32x4 acc3[2][8];

  float bo8[8], b28[8];
  #pragma unroll
  for (int ct = 0; ct < 8; ++ct) { bo8[ct] = bo[ct * 16 + lo]; b28[ct] = b2[ct * 16 + lo]; }

  // stage this wave's h0 tile (32 rows x 128) into fs via vector loads (wave-private)
  #pragma unroll
  for (int j = 0; j < 8; ++j) {
    int row = j * 4 + g;
    int n = nb + row; if (n > NN - 1) n = NN - 1;
    uint4 v = *(const uint4*)&h0b[((size_t)(b * NN + n)) * 128 + lo * 8];
    *(uint4*)&fs[(size_t)(w * 32 + row) * 136 + lo * 8] = v;
  }

  // ---------------- GEMM1: h1 = attn @ Wo^T + bo + h0 ; acc3 = h1 + b2
  #pragma unroll
  for (int s = 0; s < 2; ++s) {
    bf16x8 af[4];
    {
      int n = nb + s * 16 + lo; if (n > NN - 1) n = NN - 1;
      #pragma unroll
      for (int ks = 0; ks < 4; ++ks) {
        int hidx = ks * 2 + (g >> 1), j0 = (g & 1) * 8;
        af[ks] = *(const bf16x8*)&attnbH[((size_t)(b * HH + hidx) * NN + n) * 16 + j0];
      }
    }
    f32x4 a1[8];
    #pragma unroll
    for (int ct = 0; ct < 8; ++ct) a1[ct] = (f32x4){0.f, 0.f, 0.f, 0.f};
    #pragma unroll
    for (int ks = 0; ks < 4; ++ks) {
      #pragma unroll
      for (int ct = 0; ct < 8; ++ct) {
        bf16x8 bw = *(const bf16x8*)&Wob[(size_t)(ct * 16 + lo) * 128 + ks * 32 + g * 8];
        a1[ct] = MFMA16(af[ks], bw, a1[ct]);
      }
    }
    #pragma unroll
    for (int ct = 0; ct < 8; ++ct) {
      int d = ct * 16 + lo;
      float vals[4] = {a1[ct].x, a1[ct].y, a1[ct].z, a1[ct].w};
      #pragma unroll
      for (int r = 0; r < 4; ++r) {
        int lrow = s * 16 + g * 4 + r;
        float h0v = b2f(fs[(size_t)(w * 32 + lrow) * 136 + d]);
        float h1v = vals[r] + bo8[ct] + h0v;
        h1s[(size_t)(w * 32 + lrow) * 136 + d] = f2b(h1v);
        vals[r] = h1v + b28[ct];
      }
      acc3[s][ct] = (f32x4){vals[0], vals[1], vals[2], vals[3]};
    }
  }

  // ---------------- 4 chunks of 128 FF cols: GEMM2 (relu) + GEMM3 (accumulate)
  for (int fc = 0; fc < 4; ++fc) {
    bf16x8 a2[2][4];
    #pragma unroll
    for (int s = 0; s < 2; ++s)
      #pragma unroll
      for (int ks = 0; ks < 4; ++ks)
        a2[s][ks] = *(const bf16x8*)&h1s[(size_t)(w * 32 + s * 16 + lo) * 136 + ks * 32 + g * 8];
    f32x4 acc2[2][8];
    #pragma unroll
    for (int s = 0; s < 2; ++s)
      #pragma unroll
      for (int ct = 0; ct < 8; ++ct) acc2[s][ct] = (f32x4){0.f, 0.f, 0.f, 0.f};
    #pragma unroll
    for (int ks = 0; ks < 4; ++ks) {
      #pragma unroll
      for (int ct = 0; ct < 8; ++ct) {
        bf16x8 bw = *(const bf16x8*)&W1b[(size_t)(fc * 128 + ct * 16 + lo) * 128 + ks * 32 + g * 8];
        acc2[0][ct] = MFMA16(a2[0][ks], bw, acc2[0][ct]);
        acc2[1][ct] = MFMA16(a2[1][ks], bw, acc2[1][ct]);
      }
    }
    #pragma unroll
    for (int ct = 0; ct < 8; ++ct) {
      float b1f = b1[fc * 128 + ct * 16 + lo];
      #pragma unroll
      for (int s = 0; s < 2; ++s) {
        float vals[4] = {acc2[s][ct].x, acc2[s][ct].y, acc2[s][ct].z, acc2[s][ct].w};
        #pragma unroll
        for (int r = 0; r < 4; ++r) {
          float v = fmaxf(vals[r] + b1f, 0.0f);
          fs[(size_t)(w * 32 + s * 16 + g * 4 + r) * 136 + ct * 16 + lo] = f2b(v);
        }
      }
    }
    bf16x8 a3[2][4];
    #pragma unroll
    for (int s = 0; s < 2; ++s)
      #pragma unroll
      for (int ks = 0; ks < 4; ++ks)
        a3[s][ks] = *(const bf16x8*)&fs[(size_t)(w * 32 + s * 16 + lo) * 136 + ks * 32 + g * 8];
    #pragma unroll
    for (int ks = 0; ks < 4; ++ks) {
      #pragma unroll
      for (int ct = 0; ct < 8; ++ct) {
        bf16x8 bw = *(const bf16x8*)&W2b[(size_t)(ct * 16 + lo) * 512 + fc * 128 + ks * 32 + g * 8];
        acc3[0][ct] = MFMA16(a3[0][ks], bw, acc3[0][ct]);
        acc3[1][ct] = MFMA16(a3[1][ks], bw, acc3[1][ct]);
      }
    }
  }

  // ---------------- epilogue: stage h2 tile in LDS, coalesced transposed write
  __syncthreads();
  #pragma unroll
  for (int s = 0; s < 2; ++s)
    #pragma unroll
    for (int ct = 0; ct < 8; ++ct) {
      float vals[4] = {acc3[s][ct].x, acc3[s][ct].y, acc3[s][ct].z, acc3[s][ct].w};
      #pragma unroll
      for (int r = 0; r < 4; ++r)
        h2s[(size_t)(w * 32 + s * 16 + g * 4 + r) * 132 + ct * 16 + lo] = vals[r];
    }
  __syncthreads();
  {
    int d = tid >> 1, half = tid & 1;
    #pragma unroll
    for (int j = 0; j < 16; ++j) {
      int nl = half * 64 + j * 4;
      int n = blockIdx.x * 128 + nl;
      if (n < NN) {
        float4 v;
        v.x = h2s[(size_t)(nl + 0) * 132 + d];
        v.y = h2s[(size_t)(nl + 1) * 132 + d];
        v.z = h2s[(size_t)(nl + 2) * 132 + d];
        v.w = h2s[(size_t)(nl + 3) * 132 + d];
        *(float4*)&h2T[((size_t)(b * 128 + d)) * NN + n] = v;
      }
    }
  }
}

// ---------------------------------------------------------------- K5: glimpse MHA, 512 threads (grid == CU count: more waves/block is the only lever)
__global__ __launch_bounds__(512, 1) void k_glimpse(
    const float* __restrict__ memory, const float* __restrict__ h2T,
    const float* __restrict__ ctx, const float* __restrict__ WmT,
    const float* __restrict__ W_mem, const float* __restrict__ b_mem,
    const float* __restrict__ W_gl, const float* __restrict__ b_gl,
    float* __restrict__ gq_out, float* __restrict__ ulog_out,
    float* __restrict__ c_out) {
  int b = blockIdx.x, tid = threadIdx.x;   // 0..511
  __shared__ float qarr[128];
  __shared__ float wql[1024];
  __shared__ float qb[8];
  __shared__ float sp[8 * NN];
  __shared__ float denom[8];
  __shared__ float hsm[128 * 70];
  __shared__ float msm[128 * 70];
  __shared__ float tl[1024];
  __shared__ float ulp[512];
  __shared__ float ul[128];
  __shared__ float gol[128];
  __shared__ float gqs[128];

  if (tid < 128) qarr[tid] = ctx[b * 128 + tid];
  __syncthreads();
  for (int idx = tid; idx < 1024; idx += 512) {
    int hh = idx >> 7, e = idx & 127;
    float acc = 0.0f;
    #pragma unroll
    for (int j = 0; j < 16; ++j) acc += qarr[hh * 16 + j] * WmT[(size_t)e * 384 + hh * 16 + j];
    wql[idx] = acc;
  }
  if (tid < 8) {
    float acc = 0.0f;
    #pragma unroll
    for (int j = 0; j < 16; ++j) acc += qarr[tid * 16 + j] * b_mem[tid * 16 + j];
    qb[tid] = acc;
  }
  __syncthreads();
  // pass 1: scores (2 n per thread)
  for (int n = tid; n < NN; n += 512) {
    float a8[8];
    #pragma unroll
    for (int hh = 0; hh < 8; ++hh) a8[hh] = qb[hh];
    const float* mcol = &memory[(size_t)b * 384 * NN + n];
    for (int rr = 0; rr < 128; ++rr) a8[rr >> 4] += qarr[rr] * mcol[(size_t)rr * NN];
    const float* hcol = &h2T[(size_t)b * 128 * NN + n];
    for (int e = 0; e < 128; ++e) {
      float hv = hcol[(size_t)e * NN];
      #pragma unroll
      for (int hh = 0; hh < 8; ++hh) a8[hh] += wql[hh * 128 + e] * hv;
    }
    #pragma unroll
    for (int hh = 0; hh < 8; ++hh) sp[hh * NN + n] = 0.25f * a8[hh];
  }
  __syncthreads();
  // softmax: one full 64-lane wave per head
  {
    int hh = tid >> 6, l64 = tid & 63;
    float mx = -1e30f;
    for (int n = l64; n < NN; n += 64) mx = fmaxf(mx, sp[hh * NN + n]);
    #pragma unroll
    for (int off = 32; off >= 1; off >>= 1) mx = fmaxf(mx, __shfl_xor(mx, off));
    float sm = 0.0f;
    for (int n = l64; n < NN; n += 64) {
      float p = __expf(sp[hh * NN + n] - mx);
      sp[hh * NN + n] = p; sm += p;
    }
    #pragma unroll
    for (int off = 32; off >= 1; off >>= 1) sm += __shfl_xor(sm, off);
    if (l64 == 0) denom[hh] = sm;
  }
  __syncthreads();
  // pass 2: t[h][e] (4 quarter-groups x 2 heads) and u[j] (4-way nn split)
  float tacc[2] = {0.f, 0.f};
  float uacc = 0.0f;
  int e = tid & 127, quad = tid >> 7;   // quad 0..3
  const float2* h2T2 = (const float2*)h2T;
  const float2* mem2 = (const float2*)memory;
  for (int t = 0; t < 16; ++t) {
    int nb = t * 64;
    int nmax = (NN - nb < 64) ? (NN - nb) : 64;
    for (int idx = tid; idx < 4096; idx += 512) {
      int row = idx >> 5, c2 = idx & 31;
      int nn2 = nb + c2 * 2;
      float2 hv = make_float2(0.f, 0.f), mv = make_float2(0.f, 0.f);
      if (nn2 < NN) {
        hv = h2T2[(((size_t)b * 128 + row) * NN + nn2) >> 1];
        mv = mem2[(((size_t)b * 384 + 128 + row) * NN + nn2) >> 1];
      }
      *(float2*)&hsm[row * 70 + c2 * 2] = hv;
      *(float2*)&msm[row * 70 + c2 * 2] = mv;
    }
    __syncthreads();
    for (int nn = 0; nn < nmax; ++nn) {
      float hv = hsm[e * 70 + nn];
      #pragma unroll
      for (int hh2 = 0; hh2 < 2; ++hh2)
        tacc[hh2] += sp[(quad * 2 + hh2) * NN + nb + nn] * hv;
    }
    {
      int hj = e >> 4;
      for (int nn = quad; nn < nmax; nn += 4)
        uacc += sp[hj * NN + nb + nn] * msm[e * 70 + nn];
    }
    __syncthreads();
  }
  #pragma unroll
  for (int hh2 = 0; hh2 < 2; ++hh2) tl[(quad * 2 + hh2) * 128 + e] = tacc[hh2];
  ulp[quad * 128 + e] = uacc;
  __syncthreads();
  if (tid < 128) ul[tid] = ulp[tid] + ulp[128 + tid] + ulp[256 + tid] + ulp[384 + tid];
  __syncthreads();
  if (tid < 128) {
    int j = tid, hj = j >> 4;
    float acc = ul[j];
    const float* wrow = &W_mem[(size_t)(128 + j) * 128];
    for (int e2 = 0; e2 < 128; ++e2) acc += wrow[e2] * tl[hj * 128 + e2];
    gol[j] = acc / denom[hj] + b_mem[128 + j];
  }
  __syncthreads();
  if (tid < 128) {
    int d = tid;
    float acc = b_gl[d];
    const float* wrow = &W_gl[(size_t)d * 128];
    for (int j = 0; j < 128; ++j) acc += wrow[j] * gol[j];
    gqs[d] = acc;
    gq_out[b * 128 + d] = acc;
  }
  __syncthreads();
  if (tid < 128) {
    int e2 = tid;
    float acc = 0.0f;
    for (int dd = 0; dd < 128; ++dd) acc += WmT[(size_t)e2 * 384 + 256 + dd] * gqs[dd];
    ulog_out[b * 128 + e2] = acc;
  } else if (tid == 128) {
    float acc = 0.0f;
    for (int dd = 0; dd < 128; ++dd) acc += b_mem[256 + dd] * gqs[dd];
    c_out[b] = acc;
  }
}

// ---------------------------------------------------------------- K6: logits + log_softmax, 512 threads
__global__ __launch_bounds__(512) void k_logits(
    const float* __restrict__ memory, const float* __restrict__ h2T,
    const float* __restrict__ gq, const float* __restrict__ ulog,
    const float* __restrict__ cbuf, const float* __restrict__ mask,
    float* __restrict__ out) {
  int b = blockIdx.x, tid = threadIdx.x;   // 0..511
  __shared__ float gql[128], ull[128];
  __shared__ float lg[NN];
  __shared__ float red[512];
  if (tid < 128) { gql[tid] = gq[b * 128 + tid]; ull[tid] = ulog[b * 128 + tid]; }
  __syncthreads();
  float cb = cbuf[b];
  float lmax = -1e30f;
  for (int n = tid; n < NN; n += 512) {
    float a1 = 0.0f, a2 = 0.0f;
    const float* mcol = &memory[((size_t)b * 384 + 256) * NN + n];
    const float* hcol = &h2T[(size_t)b * 128 * NN + n];
    for (int r = 0; r < 128; ++r) {
      a1 += mcol[(size_t)r * NN] * gql[r];
      a2 += hcol[(size_t)r * NN] * ull[r];
    }
    float z = (a1 + a2 + cb) * 0.088388347648318447f;
    float lv = tanhf(z) * CLIPV + logf(mask[(size_t)b * NN + n]);
    lg[n] = lv;
    lmax = fmaxf(lmax, lv);
  }
  red[tid] = lmax; __syncthreads();
  for (int s2 = 256; s2 >= 1; s2 >>= 1) {
    if (tid < s2) red[tid] = fmaxf(red[tid], red[tid + s2]);
    __syncthreads();
  }
  float mm = red[0];
  __syncthreads();
  float ls = 0.0f;
  for (int n = tid; n < NN; n += 512) ls += __expf(lg[n] - mm);
  red[tid] = ls; __syncthreads();
  for (int s2 = 256; s2 >= 1; s2 >>= 1) {
    if (tid < s2) red[tid] += red[tid + s2];
    __syncthreads();
  }
  float logS = logf(red[0]);
  __syncthreads();
  for (int n = tid; n < NN; n += 512) out[(size_t)b * NN + n] = lg[n] - mm - logS;
}

// ---------------------------------------------------------------- launch
extern "C" void kernel_launch(void* const* d_in, const int* in_sizes, int n_in,
                              void* d_out, int out_size, void* d_ws, size_t ws_size,
                              hipStream_t stream) {
  (void)in_sizes; (void)n_in; (void)out_size; (void)ws_size;
  const float* location = (const float*)d_in[0];
  const float* max_load = (const float*)d_in[1];
  const float* speed    = (const float*)d_in[2];
  const int*   next_agent = (const int*)d_in[3];
  const int*   position = (const int*)d_in[4];
  const float* tta      = (const float*)d_in[5];
  const float* load     = (const float*)d_in[6];
  const float* demand   = (const float*)d_in[7];
  const float* mask     = (const float*)d_in[8];
  const float* nef      = (const float*)d_in[9];
  const float* depot    = (const float*)d_in[10];
  const float* graph    = (const float*)d_in[11];
  const float* memory   = (const float*)d_in[12];
  const float* W_na     = (const float*)d_in[13];
  const float* b_na     = (const float*)d_in[14];
  const float* Wq       = (const float*)d_in[15];
  const float* bq       = (const float*)d_in[16];
  const float* Wk       = (const float*)d_in[17];
  const float* bk       = (const float*)d_in[18];
  const float* Wv       = (const float*)d_in[19];
  const float* bv       = (const float*)d_in[20];
  const float* Wo       = (const float*)d_in[21];
  const float* bo       = (const float*)d_in[22];
  const float* W_ff1    = (const float*)d_in[23];
  const float* b_ff1    = (const float*)d_in[24];
  const float* W_ff2    = (const float*)d_in[25];
  const float* b_ff2    = (const float*)d_in[26];
  const float* W_mem    = (const float*)d_in[27];
  const float* b_mem    = (const float*)d_in[28];
  const float* W_ctx    = (const float*)d_in[29];
  const float* b_ctx    = (const float*)d_in[30];
  const float* W_gl     = (const float*)d_in[31];
  const float* b_gl     = (const float*)d_in[32];

  float* p = (float*)d_ws;
  float* WmT = p;  p += 49152;
  u16*  Wqkvb = (u16*)p; p += 24576;
  u16*  Wob = (u16*)p;   p += 8192;
  u16*  W1b = (u16*)p;   p += 32768;
  u16*  W2b = (u16*)p;   p += 32768;
  float* ctx = p;  p += (size_t)BB * 128;
  float* gqb = p;  p += (size_t)BB * 128;
  float* ulb = p;  p += (size_t)BB * 128;
  float* cb  = p;  p += BB;
  u16*  h0b = (u16*)p;  p += (size_t)BB * NN * 64;    // bf16 [B,N,128]
  u16*  attnbH = (u16*)p; p += (size_t)BB * NN * 64;  // bf16 [B*H,N,16]
  u16*  Vh  = (u16*)p;  p += (size_t)BB * NN * 64;    // bf16 [B*H,N,16]
  float* h2t = p;  p += (size_t)BB * 128 * NN;
  // Qh/Kh alias h2t (dead before k_ff2 writes h2t)
  u16* Qh = (u16*)h2t;
  u16* Kh = (u16*)(h2t + (size_t)BB * NN * 64);

  hipLaunchKernelGGL(k_transpose, dim3(256), dim3(256), 0, stream,
                     Wo, W_ff1, W_ff2, W_mem, Wq, Wk, Wv, WmT, Wqkvb, Wob, W1b, W2b);
  hipLaunchKernelGGL(k_setup, dim3(BB), dim3(256), 0, stream,
                     location, max_load, speed, next_agent, position, load,
                     nef, depot, graph, W_ctx, b_ctx, ctx);
  hipLaunchKernelGGL(k_ne, dim3(63, BB), dim3(128), 0, stream,
                     location, next_agent, position, tta, load, demand, speed,
                     W_na, b_na, h0b);
  hipLaunchKernelGGL(k_qkv, dim3(16, BB), dim3(256), 0, stream,
                     h0b, Wqkvb, bq, bk, bv, Qh, Kh, Vh);
  hipLaunchKernelGGL(k_attn9, dim3(HH, BB), dim3(256), 0, stream,
                     Qh, Kh, Vh, attnbH);
  hipLaunchKernelGGL(k_ff2, dim3(8, BB), dim3(256), 0, stream,
                     h0b, attnbH, Wob, bo, W1b, b_ff1, W2b, b_ff2, h2t);
  hipLaunchKernelGGL(k_glimpse, dim3(BB), dim3(512), 0, stream,
                     memory, h2t, ctx, WmT, W_mem, b_mem, W_gl, b_gl, gqb, ulb, cb);
  hipLaunchKernelGGL(k_logits, dim3(BB), dim3(512), 0, stream,
                     memory, h2t, gqb, ulb, cb, mask, (float*)d_out);
}